// Round 15
// baseline (373.653 us; speedup 1.0000x reference)
//
#include <hip/hip_runtime.h>
#include <math.h>

#define NN 50000
#define EE 640000
#define EP (EE + NN)
#define GG 128
#define IND 128
#define LATC 32
#define HH 8
#define HLC 256
#define HIDN 128
#define SCAN_B 256
#define SCAN_G ((NN + SCAN_B - 1) / SCAN_B)  // 196
#define AGP_BLOCKS 2048

typedef unsigned short ushortT;
typedef unsigned int uintT;
typedef short bf16x8 __attribute__((ext_vector_type(8)));
typedef float f32x4 __attribute__((ext_vector_type(4)));

__device__ __forceinline__ float elu1(float v) { return v > 0.f ? v : (__expf(v) - 1.f); }

__device__ __forceinline__ ushortT f2bf(float f) {  // round-to-nearest-even
  unsigned int u = __float_as_uint(f);
  return (ushortT)((u + 0x7fffu + ((u >> 16) & 1u)) >> 16);
}
__device__ __forceinline__ float bf2f(ushortT s) {
  return __uint_as_float(((unsigned int)s) << 16);
}

// ---- CSR build ----------------------------------------------------------
__global__ void count_kernel(const int* col, int* cnt) {
  int t = blockIdx.x * blockDim.x + threadIdx.x;
  if (t < EE) atomicAdd(&cnt[col[t]], 1);
}

// hierarchical exclusive scan over (cnt[i]+1): part -> top -> final
__global__ void scan_part_kernel(const int* __restrict__ cnt,
                                 int* __restrict__ bsum) {
  int t = threadIdx.x;
  int i = blockIdx.x * SCAN_B + t;
  int v = (i < NN) ? cnt[i] + 1 : 0;  // +1 = self-loop
#pragma unroll
  for (int d = 1; d < 64; d <<= 1) v += __shfl_xor(v, d);
  __shared__ int ws[4];
  if ((t & 63) == 0) ws[t >> 6] = v;
  __syncthreads();
  if (t == 0) bsum[blockIdx.x] = ws[0] + ws[1] + ws[2] + ws[3];
}

__global__ void scan_top_kernel(const int* __restrict__ bsum,
                                int* __restrict__ ebsum,
                                int* __restrict__ offs_last) {
  int t = threadIdx.x;  // 256 threads, SCAN_G=196 values
  int v = (t < SCAN_G) ? bsum[t] : 0;
  int orig = v;
  int lane = t & 63, w = t >> 6;
#pragma unroll
  for (int d = 1; d < 64; d <<= 1) {
    int o = __shfl_up(v, d);
    if (lane >= d) v += o;
  }
  __shared__ int ws[4];
  if (lane == 63) ws[w] = v;
  __syncthreads();
  int add = 0;
  for (int j = 0; j < w; ++j) add += ws[j];
  v += add;
  if (t < SCAN_G) ebsum[t] = v - orig;   // exclusive block prefix
  if (t == SCAN_G - 1) *offs_last = v;   // total = EP
}

__global__ void scan_final_kernel(const int* __restrict__ cnt,
                                  const int* __restrict__ ebsum,
                                  int* __restrict__ offs,
                                  float* __restrict__ dinv) {
  int t = threadIdx.x;
  int i = blockIdx.x * SCAN_B + t;
  int v = (i < NN) ? cnt[i] + 1 : 0;
  int orig = v;
  int lane = t & 63, w = t >> 6;
#pragma unroll
  for (int d = 1; d < 64; d <<= 1) {
    int o = __shfl_up(v, d);
    if (lane >= d) v += o;
  }
  __shared__ int ws[4];
  if (lane == 63) ws[w] = v;
  __syncthreads();
  int add = ebsum[blockIdx.x];
  for (int j = 0; j < w; ++j) add += ws[j];
  if (i < NN) {
    offs[i] = v - orig + add;            // exclusive scan
    dinv[i] = 1.f / sqrtf((float)orig);  // deg incl. self-loop
  }
}

__global__ void build_kernel(const int* row, const int* col, const int* offs,
                             int* cursor, int* srcs) {
  int t = blockIdx.x * blockDim.x + threadIdx.x;
  if (t >= EP) return;
  int r, c;
  if (t < EE) { r = row[t]; c = col[t]; } else { r = t - EE; c = r; }
  int pos = offs[c] + atomicAdd(&cursor[c], 1);
  srcs[pos] = r;
}

// one WAVE per node: 64-wide bitonic shuffle sort (canonical order ->
// deterministic FP sums); serial fallback for deg>64 (never hit here).
__global__ void finalize_kernel(const int* offs, int* srcs) {
  int gw = (blockIdx.x * blockDim.x + threadIdx.x) >> 6;
  if (gw >= NN) return;
  int lane = threadIdx.x & 63;
  int beg = offs[gw], end = offs[gw + 1];
  int deg = end - beg;
  if (deg <= 64) {
    int v = (lane < deg) ? srcs[beg + lane] : 0x7fffffff;
    for (int k = 2; k <= 64; k <<= 1)
      for (int j = k >> 1; j > 0; j >>= 1) {
        int o = __shfl_xor(v, j);
        bool keepmin = (((lane & k) == 0) == ((lane & j) == 0));
        v = keepmin ? (v < o ? v : o) : (v > o ? v : o);
      }
    if (lane < deg) srcs[beg + lane] = v;
  } else if (lane == 0) {
    for (int i = beg + 1; i < end; ++i) {
      int v = srcs[i]; int j = i - 1;
      while (j >= beg && srcs[j] > v) { srcs[j + 1] = srcs[j]; --j; }
      srcs[j + 1] = v;
    }
  }
}

// ---- GAT1 prep: va[h*32+c] = sum_j Wg1[c][h*32+j]*asrc[h*32+j] ---------
__global__ void prep_kernel(const float* __restrict__ Wg1,
                            const float* __restrict__ asrc,
                            const float* __restrict__ adst, float* va,
                            float* vb) {
  int t = threadIdx.x;  // 256 = 8 heads x 32 c
  int c = t & 31, h = t >> 5;
  float sa = 0.f, sb = 0.f;
  for (int j = 0; j < 32; ++j) {
    float w = Wg1[(size_t)c * HLC + h * 32 + j];
    sa += w * asrc[h * 32 + j];
    sb += w * adst[h * 32 + j];
  }
  va[t] = sa;  // t = h*32+c
  vb[t] = sb;
}

// ---- x@W1: [N,128] @ [128,32], 256 rows/block, 8x4 per thread ----------
__launch_bounds__(256)
__global__ void gemm_in_kernel(const float* __restrict__ A,
                               const float* __restrict__ W,
                               float* __restrict__ out) {
  __shared__ float As[32][264];
  __shared__ float Bs[32][32];
  int bm = blockIdx.x * 256;
  int tid = threadIdx.x;
  int tx = tid & 7, ty = tid >> 3;
  float acc[8][4] = {};
  for (int k0 = 0; k0 < IND; k0 += 32) {
    {
      int gm = bm + tid;
      bool ok = gm < NN;
#pragma unroll
      for (int j = 0; j < 8; ++j) {
        float4 v = ok ? *(const float4*)(A + (size_t)gm * IND + k0 + j * 4)
                      : make_float4(0.f, 0.f, 0.f, 0.f);
        As[j * 4 + 0][tid] = v.x; As[j * 4 + 1][tid] = v.y;
        As[j * 4 + 2][tid] = v.z; As[j * 4 + 3][tid] = v.w;
      }
    }
#pragma unroll
    for (int j = 0; j < 4; ++j) {
      int idx = tid + j * 256;
      int kk = idx >> 5, c = idx & 31;
      Bs[kk][c] = W[(size_t)(k0 + kk) * LATC + c];
    }
    __syncthreads();
#pragma unroll 4
    for (int kk = 0; kk < 32; ++kk) {
      float4 a0 = *(const float4*)(&As[kk][ty * 8]);
      float4 a1 = *(const float4*)(&As[kk][ty * 8 + 4]);
      float4 b = *(const float4*)(&Bs[kk][tx * 4]);
      float ar[8] = {a0.x, a0.y, a0.z, a0.w, a1.x, a1.y, a1.z, a1.w};
      float bc[4] = {b.x, b.y, b.z, b.w};
#pragma unroll
      for (int i = 0; i < 8; ++i)
#pragma unroll
        for (int j = 0; j < 4; ++j) acc[i][j] += ar[i] * bc[j];
    }
    __syncthreads();
  }
#pragma unroll
  for (int i = 0; i < 8; ++i) {
    int gm = bm + ty * 8 + i;
    if (gm < NN)
      *(float4*)(out + (size_t)gm * LATC + tx * 4) =
          make_float4(acc[i][0], acc[i][1], acc[i][2], acc[i][3]);
  }
}

// ---- Wg2 pre-split: WhT/WlT[n][k] bf16 hi/lo (transposed) --------------
__global__ void wsplit_kernel(const float* __restrict__ Wg2,
                              ushortT* __restrict__ WhT,
                              ushortT* __restrict__ WlT) {
  int idx = blockIdx.x * 256 + threadIdx.x;
  if (idx >= HLC * HLC) return;
  int k = idx >> 8, n = idx & 255;
  float f = Wg2[idx];
  ushortT hi = f2bf(f);
  WhT[n * HLC + k] = hi;
  WlT[n * HLC + k] = f2bf(f - bf2f(hi));
}

// ---- GAT2 GEMM via split-bf16 MFMA (3 mfma ~ fp32 accuracy) ------------
__launch_bounds__(256)
__global__ void gemm_gat2_mfma(const float* __restrict__ A,
                               const ushortT* __restrict__ WhT,
                               const ushortT* __restrict__ WlT,
                               const float* __restrict__ asrc,
                               const float* __restrict__ adst,
                               ushortT* __restrict__ hgb,
                               float* __restrict__ sbuf,
                               float* __restrict__ dbuf) {
  __shared__ __align__(16) char smem[51200];
  ushortT* Ah = (ushortT*)smem;             // [64][40]
  ushortT* Al = Ah + 64 * 40;               // [64][40]  (ends at 10240B)
  ushortT* Bh = (ushortT*)(smem + 10240);   // [256][40]
  ushortT* Bl = Bh + 256 * 40;              // [256][40] (ends at 51200B)
  float* LDSf = (float*)(smem + 10240);     // overlay: [32][260] f32 (33280B)

  int tid = threadIdx.x;
  int lane = tid & 63;
  int w = tid >> 6;          // wave 0..3 -> col quadrant
  int l15 = lane & 15, lg = lane >> 4;
  int bm = blockIdx.x * 64;

  f32x4 zero4 = {0.f, 0.f, 0.f, 0.f};
  f32x4 acc[4][4];
#pragma unroll
  for (int mi = 0; mi < 4; ++mi)
#pragma unroll
    for (int ni = 0; ni < 4; ++ni) acc[mi][ni] = zero4;

  for (int k0 = 0; k0 < HLC; k0 += 32) {
    // stage A rows (fp32 -> hi/lo bf16)
    {
      int row = tid >> 2, kb = (tid & 3) * 8;
      int gm = bm + row;
      float f[8];
      if (gm < NN) {
        float4 u0 = *(const float4*)(A + (size_t)gm * HLC + k0 + kb);
        float4 u1 = *(const float4*)(A + (size_t)gm * HLC + k0 + kb + 4);
        f[0] = u0.x; f[1] = u0.y; f[2] = u0.z; f[3] = u0.w;
        f[4] = u1.x; f[5] = u1.y; f[6] = u1.z; f[7] = u1.w;
      } else {
#pragma unroll
        for (int j = 0; j < 8; ++j) f[j] = 0.f;
      }
      bf16x8 vh, vl;
#pragma unroll
      for (int j = 0; j < 8; ++j) {
        ushortT hi = f2bf(f[j]);
        vh[j] = (short)hi;
        vl[j] = (short)f2bf(f[j] - bf2f(hi));
      }
      *(bf16x8*)(Ah + row * 40 + kb) = vh;
      *(bf16x8*)(Al + row * 40 + kb) = vl;
    }
    // stage B slice from pre-split WhT/WlT (n = tid, 32 consecutive k)
    {
      const bf16x8* ph = (const bf16x8*)(WhT + (size_t)tid * HLC + k0);
      const bf16x8* pl = (const bf16x8*)(WlT + (size_t)tid * HLC + k0);
#pragma unroll
      for (int i = 0; i < 4; ++i) {
        *(bf16x8*)(Bh + tid * 40 + i * 8) = ph[i];
        *(bf16x8*)(Bl + tid * 40 + i * 8) = pl[i];
      }
    }
    __syncthreads();
    bf16x8 ah[4], al[4], bh[4], bl[4];
#pragma unroll
    for (int mi = 0; mi < 4; ++mi) {
      int off = (mi * 16 + l15) * 40 + lg * 8;
      ah[mi] = *(const bf16x8*)(Ah + off);
      al[mi] = *(const bf16x8*)(Al + off);
    }
#pragma unroll
    for (int ni = 0; ni < 4; ++ni) {
      int off = (w * 64 + ni * 16 + l15) * 40 + lg * 8;
      bh[ni] = *(const bf16x8*)(Bh + off);
      bl[ni] = *(const bf16x8*)(Bl + off);
    }
#pragma unroll
    for (int mi = 0; mi < 4; ++mi)
#pragma unroll
      for (int ni = 0; ni < 4; ++ni) {
        acc[mi][ni] = __builtin_amdgcn_mfma_f32_16x16x32_bf16(
            al[mi], bh[ni], acc[mi][ni], 0, 0, 0);
        acc[mi][ni] = __builtin_amdgcn_mfma_f32_16x16x32_bf16(
            ah[mi], bl[ni], acc[mi][ni], 0, 0, 0);
        acc[mi][ni] = __builtin_amdgcn_mfma_f32_16x16x32_bf16(
            ah[mi], bh[ni], acc[mi][ni], 0, 0, 0);
      }
    __syncthreads();
  }

  // ---- s/d epilogue from fp32 acc (exact logits) ----
  float av[4], bv[4];
#pragma unroll
  for (int ni = 0; ni < 4; ++ni) {
    int c = w * 64 + ni * 16 + l15;
    av[ni] = asrc[c];
    bv[ni] = adst[c];
  }
#pragma unroll
  for (int mi = 0; mi < 4; ++mi)
#pragma unroll
    for (int r = 0; r < 4; ++r) {
      int gm = bm + mi * 16 + lg * 4 + r;
      float s0 = acc[mi][0][r] * av[0] + acc[mi][1][r] * av[1];
      float s1 = acc[mi][2][r] * av[2] + acc[mi][3][r] * av[3];
      float d0 = acc[mi][0][r] * bv[0] + acc[mi][1][r] * bv[1];
      float d1 = acc[mi][2][r] * bv[2] + acc[mi][3][r] * bv[3];
#pragma unroll
      for (int m = 1; m <= 8; m <<= 1) {
        s0 += __shfl_xor(s0, m);
        s1 += __shfl_xor(s1, m);
        d0 += __shfl_xor(d0, m);
        d1 += __shfl_xor(d1, m);
      }
      if (l15 == 0 && gm < NN) {
        sbuf[gm * HH + 2 * w] = s0;
        sbuf[gm * HH + 2 * w + 1] = s1;
        dbuf[gm * HH + 2 * w] = d0;
        dbuf[gm * HH + 2 * w + 1] = d1;
      }
    }

  // ---- hg bf16 store via LDS repack (two 32-row passes) ----
#pragma unroll
  for (int p = 0; p < 2; ++p) {
    __syncthreads();
#pragma unroll
    for (int q = 0; q < 2; ++q) {
      int mi = 2 * p + q;
#pragma unroll
      for (int ni = 0; ni < 4; ++ni)
#pragma unroll
        for (int r = 0; r < 4; ++r) {
          int lrow = q * 16 + lg * 4 + r;
          LDSf[lrow * 260 + w * 64 + ni * 16 + l15] = acc[mi][ni][r];
        }
    }
    __syncthreads();
    int row = tid >> 3, cb = (tid & 7) * 32;
    int gm = bm + p * 32 + row;
    if (gm < NN) {
      uintT u[16];
#pragma unroll
      for (int i = 0; i < 8; ++i) {
        float4 v = *(const float4*)(LDSf + row * 260 + cb + i * 4);
        u[2 * i] = (uintT)f2bf(v.x) | ((uintT)f2bf(v.y) << 16);
        u[2 * i + 1] = (uintT)f2bf(v.z) | ((uintT)f2bf(v.w) << 16);
      }
      uintT* dst = (uintT*)(hgb + (size_t)gm * HLC + cb);
#pragma unroll
      for (int i = 0; i < 4; ++i) {
        uint4 s;
        s.x = u[4 * i]; s.y = u[4 * i + 1];
        s.z = u[4 * i + 2]; s.w = u[4 * i + 3];
        *(uint4*)(dst + 4 * i) = s;
      }
    }
  }
}

// ---- FUSED GCN aggregate + GAT1 s/d logits (va/vb precomputed) ---------
__global__ void gcn_agg_sd_kernel(const float* __restrict__ hW,
                                  const int* offs, const int* srcs,
                                  const float* dinv, const float* b1,
                                  const float* __restrict__ vag,
                                  const float* __restrict__ vbg,
                                  float* h1, float* s, float* d) {
  __shared__ float va[HLC], vb[HLC];
  __shared__ float rowbuf[4][LATC];
  int t = threadIdx.x;
  va[t] = vag[t];  // coalesced 2KB stage
  vb[t] = vbg[t];
  __syncthreads();
  int wid = (blockIdx.x * blockDim.x + t) >> 6;
  int lane = t & 63;
  int wv = t >> 6;
  int c = lane & 31, half = lane >> 5;
  int beg = offs[wid], end = offs[wid + 1];
  float acc = 0.f;
  for (int p = beg + half; p < end; p += 2) {
    int src = srcs[p];
    acc += dinv[src] * hW[src * LATC + c];
  }
  acc += __shfl_xor(acc, 32);
  if (lane < 32) {
    float v = elu1(dinv[wid] * acc + b1[c]);
    h1[wid * LATC + c] = v;
    rowbuf[wv][c] = v;  // same-wave LDS: no barrier needed
  }
  int h = lane >> 3, k = lane & 7;
  float ps = 0.f, pd = 0.f;
#pragma unroll
  for (int j = 0; j < 4; ++j) {
    float x = rowbuf[wv][k * 4 + j];
    ps += x * va[h * 32 + k * 4 + j];
    pd += x * vb[h * 32 + k * 4 + j];
  }
  ps += __shfl_xor(ps, 1); pd += __shfl_xor(pd, 1);
  ps += __shfl_xor(ps, 2); pd += __shfl_xor(pd, 2);
  ps += __shfl_xor(ps, 4); pd += __shfl_xor(pd, 4);
  if (k == 0) {
    s[wid * HH + h] = ps;
    d[wid * HH + h] = pd;
  }
}

// ---- FUSED GAT1 aggregate + projection, register-resident Wg1 ----------
// 4 waves gather 4 nodes into swizzled aggs[wv][h*33+c] (bank-clean),
// barrier, then all 256 threads project: thread t owns output col t and
// holds Wg1[:,t] (32 floats) in VGPRs -> zero LDS weight traffic.
__launch_bounds__(256)
__global__ void gat1_aggproj_kernel(const float* __restrict__ h1,
                                    const float* __restrict__ s,
                                    const float* __restrict__ d,
                                    const int* offs, const int* srcs,
                                    const float* __restrict__ Wg1,
                                    const float* __restrict__ bg,
                                    float* __restrict__ h2) {
  __shared__ float aggs[4][264];  // head stride 33 -> distinct banks
  int t = threadIdx.x;
  float Wcol[32];
#pragma unroll
  for (int c = 0; c < 32; ++c) Wcol[c] = Wg1[(size_t)c * HLC + t];
  float bias = bg[t];
  int hp = t >> 5;  // head of output col t
  int lane = t & 63;
  int wv = t >> 6;
  int g = lane >> 5, l5 = lane & 31;
  int h = l5 >> 2, c8 = (l5 & 3) * 8;
  for (int big = blockIdx.x * 4; big < NN; big += AGP_BLOCKS * 4) {
    int wid = big + wv;
    if (wid < NN) {
      int beg = offs[wid], end = offs[wid + 1];
      float dn = d[wid * HH + h];
      float self = s[wid * HH + h] + dn;
      float m = self > 0.f ? self : 0.2f * self;  // self-loop present
      float z = 0.f;
      float a[8] = {};
#pragma unroll 2
      for (int p = beg + g; p < end; p += 2) {
        int src = srcs[p];
        float sv = s[src * HH + h] + dn;
        float logit = sv > 0.f ? sv : 0.2f * sv;
        float e = __expf(logit - m);
        z += e;
        float4 v0 = *(const float4*)(h1 + (size_t)src * LATC + c8);
        float4 v1 = *(const float4*)(h1 + (size_t)src * LATC + c8 + 4);
        a[0] += e * v0.x; a[1] += e * v0.y; a[2] += e * v0.z; a[3] += e * v0.w;
        a[4] += e * v1.x; a[5] += e * v1.y; a[6] += e * v1.z; a[7] += e * v1.w;
      }
      z += __shfl_xor(z, 32);
#pragma unroll
      for (int j = 0; j < 8; ++j) a[j] += __shfl_xor(a[j], 32);
      if (g == 0) {
        float zinv = 1.f / (z + 1e-16f);
#pragma unroll
        for (int j = 0; j < 8; ++j)
          aggs[wv][h * 33 + c8 + j] = a[j] * zinv;
      }
    }
    __syncthreads();
#pragma unroll
    for (int n = 0; n < 4; ++n) {
      int nd = big + n;
      if (nd < NN) {
        float o = bias;
#pragma unroll
        for (int c = 0; c < 32; ++c) o += aggs[n][hp * 33 + c] * Wcol[c];
        h2[(size_t)nd * HLC + t] = elu1(o);  // coalesced 1KB row store
      }
    }
    __syncthreads();
  }
}

// ---- GAT2 aggregate: bf16 hg gather, one wave per node -----------------
__global__ void gat_agg_kernel(const ushortT* __restrict__ hgb,
                               const float* __restrict__ s,
                               const float* __restrict__ dd, const int* offs,
                               const int* srcs, const float* bg, float* out) {
  int wid = (blockIdx.x * blockDim.x + threadIdx.x) >> 6;
  if (wid >= NN) return;
  int lane = threadIdx.x & 63;
  int hh = lane >> 3;
  int ch = lane << 2;
  int beg = offs[wid], end = offs[wid + 1];
  float dn = dd[wid * HH + hh];
  float self = s[wid * HH + hh] + dn;
  float m = self > 0.f ? self : 0.2f * self;
  float z = 0.f;
  float ax = 0.f, ay = 0.f, az = 0.f, aw = 0.f;
#pragma unroll 4
  for (int p = beg; p < end; ++p) {
    int src = srcs[p];
    float xv = s[src * HH + hh] + dn;
    float logit = xv > 0.f ? xv : 0.2f * xv;
    float e = __expf(logit - m);
    z += e;
    ushort4 v = *(const ushort4*)(hgb + (size_t)src * HLC + ch);
    ax += e * bf2f(v.x); ay += e * bf2f(v.y);
    az += e * bf2f(v.z); aw += e * bf2f(v.w);
  }
  float zinv = 1.f / (z + 1e-16f);
  float4 bb = *(const float4*)(bg + ch);
  float4 o;
  o.x = elu1(ax * zinv + bb.x); o.y = elu1(ay * zinv + bb.y);
  o.z = elu1(az * zinv + bb.z); o.w = elu1(aw * zinv + bb.w);
  *(float4*)(out + (size_t)wid * HLC + ch) = o;
}

// ---- readout head + fused loss (last-block ticket) ---------------------
__global__ void head_kernel(const float* __restrict__ h1,
                            const float* __restrict__ h2,
                            const float* __restrict__ h3, const int* batch,
                            const int* y, const float* __restrict__ Wl1,
                            const float* bl1, const float* __restrict__ Wl2,
                            const float* bl2, float* out, float* lterms,
                            int* done) {
  int g = blockIdx.x, tid = threadIdx.x;
  __shared__ float cat[544];
  __shared__ float hidden[HIDN];
  __shared__ float raw_s[2];
  __shared__ int idx_s;
  if (tid == 0) {
    int lo = 0, hi = NN;
    while (lo < hi) { int mid = (lo + hi) >> 1; if (batch[mid] < g) lo = mid + 1; else hi = mid; }
    idx_s = lo;
  }
  __syncthreads();
  int idx = idx_s;
  if (tid < 32) cat[tid] = h1[idx * LATC + tid];
  for (int i = tid; i < HLC; i += HIDN) {
    cat[32 + i] = h2[(size_t)idx * HLC + i];
    cat[288 + i] = h3[(size_t)idx * HLC + i];
  }
  __syncthreads();
  float f = bl1[tid];
  for (int k = 0; k < 544; ++k) f += cat[k] * Wl1[k * HIDN + tid];
  out[641 + g * HIDN + tid] = f;
  hidden[tid] = elu1(f);
  __syncthreads();
  if (tid < 2) {
    float r = bl2[tid];
    for (int j = 0; j < HIDN; ++j) r += hidden[j] * Wl2[j * 2 + tid];
    raw_s[tid] = r;
  }
  __syncthreads();
  if (tid == 0) {
    float r0 = raw_s[0], r1 = raw_s[1];
    float mx = fmaxf(r0, r1);
    float e0 = expf(r0 - mx), e1 = expf(r1 - mx);
    float zz = e0 + e1;
    float lse = mx + logf(zz);
    float lg0 = r0 - lse, lg1 = r1 - lse;
    out[g * 2 + 0] = lg0; out[g * 2 + 1] = lg1;
    out[385 + g * 2 + 0] = e0 / zz; out[385 + g * 2 + 1] = e1 / zz;
    out[257 + g] = (r1 > r0) ? 1.f : 0.f;
    lterms[g] = -((y[g] == 0) ? lg0 : lg1);
    __threadfence();
    int ticket = atomicAdd(done, 1);
    if (ticket == GG - 1) {  // last graph: deterministic fixed-order sum
      __threadfence();
      float sum = 0.f;
      for (int j = 0; j < GG; ++j) sum += lterms[j];
      out[256] = sum / (float)GG;
    }
  }
}

// ------------------------------------------------------------------------
extern "C" void kernel_launch(void* const* d_in, const int* in_sizes, int n_in,
                              void* d_out, int out_size, void* d_ws,
                              size_t ws_size, hipStream_t stream) {
  const float* x = (const float*)d_in[0];
  const int* ei = (const int*)d_in[1];
  const int* batch = (const int*)d_in[2];
  const int* y = (const int*)d_in[3];
  const float* W1 = (const float*)d_in[4];
  const float* b1 = (const float*)d_in[5];
  const float* Wg1 = (const float*)d_in[6];
  const float* asrc1 = (const float*)d_in[7];
  const float* adst1 = (const float*)d_in[8];
  const float* bg1 = (const float*)d_in[9];
  const float* Wg2 = (const float*)d_in[10];
  const float* asrc2 = (const float*)d_in[11];
  const float* adst2 = (const float*)d_in[12];
  const float* bg2 = (const float*)d_in[13];
  const float* Wl1 = (const float*)d_in[14];
  const float* bl1 = (const float*)d_in[15];
  const float* Wl2 = (const float*)d_in[16];
  const float* bl2 = (const float*)d_in[17];
  float* out = (float*)d_out;

  const int* erow = ei;
  const int* ecol = ei + EE;

  char* p = (char*)d_ws;
  auto alloc = [&](size_t bytes) {
    void* r = (void*)p;
    p += (bytes + 255) & ~(size_t)255;
    return r;
  };
  int* cntcur = (int*)alloc(((size_t)2 * NN + 64) * 4);  // cnt|cursor|done
  int* cnt = cntcur;
  int* cursor = cntcur + NN;
  int* done = cntcur + 2 * NN;
  int* offs = (int*)alloc((NN + 1) * 4);
  int* srcs = (int*)alloc((size_t)EP * 4);
  int* bsum = (int*)alloc(SCAN_G * 4);
  int* ebsum = (int*)alloc(SCAN_G * 4);
  float* dinv = (float*)alloc(NN * 4);
  float* hW = (float*)alloc((size_t)NN * LATC * 4);
  float* h1 = (float*)alloc((size_t)NN * LATC * 4);
  float* hg = (float*)alloc((size_t)NN * HLC * 4);  // hgb (bf16) backing
  float* h2 = (float*)alloc((size_t)NN * HLC * 4);
  float* h3 = (float*)alloc((size_t)NN * HLC * 4);
  float* sbuf = (float*)alloc((size_t)NN * HH * 4);
  float* dbuf = (float*)alloc((size_t)NN * HH * 4);
  float* va = (float*)alloc(HLC * 4);
  float* vb = (float*)alloc(HLC * 4);
  float* lterms = (float*)alloc(GG * 4);
  ushortT* whT = (ushortT*)alloc((size_t)HLC * HLC * 2);
  ushortT* wlT = (ushortT*)alloc((size_t)HLC * HLC * 2);
  ushortT* hgb = (ushortT*)hg;

  const int NBLK = (NN + 63) / 64;  // 782

  // CSR (reused by all three conv layers)
  hipMemsetAsync(cntcur, 0, ((size_t)2 * NN + 64) * 4, stream);
  count_kernel<<<(EE + 255) / 256, 256, 0, stream>>>(ecol, cnt);
  scan_part_kernel<<<SCAN_G, SCAN_B, 0, stream>>>(cnt, bsum);
  scan_top_kernel<<<1, 256, 0, stream>>>(bsum, ebsum, offs + NN);
  scan_final_kernel<<<SCAN_G, SCAN_B, 0, stream>>>(cnt, ebsum, offs, dinv);
  build_kernel<<<(EP + 255) / 256, 256, 0, stream>>>(erow, ecol, offs, cursor, srcs);
  finalize_kernel<<<(NN + 3) / 4, 256, 0, stream>>>(offs, srcs);

  // independent weight prep
  wsplit_kernel<<<(HLC * HLC + 255) / 256, 256, 0, stream>>>(Wg2, whT, wlT);
  prep_kernel<<<1, 256, 0, stream>>>(Wg1, asrc1, adst1, va, vb);

  // GCN (+ fused GAT1 s/d logits, va/vb from global)
  gemm_in_kernel<<<(NN + 255) / 256, 256, 0, stream>>>(x, W1, hW);
  gcn_agg_sd_kernel<<<(NN + 3) / 4, 256, 0, stream>>>(
      hW, offs, srcs, dinv, b1, va, vb, h1, sbuf, dbuf);

  // GAT 1 — fused gather + register-weight projection -> h2
  gat1_aggproj_kernel<<<AGP_BLOCKS, 256, 0, stream>>>(h1, sbuf, dbuf, offs,
                                                      srcs, Wg1, bg1, h2);

  // GAT 2 — split-bf16 MFMA GEMM + exact s/d epilogue + bf16 hg
  gemm_gat2_mfma<<<NBLK, 256, 0, stream>>>(h2, whT, wlT, asrc2, adst2, hgb,
                                           sbuf, dbuf);
  gat_agg_kernel<<<(NN + 3) / 4, 256, 0, stream>>>(hgb, sbuf, dbuf, offs, srcs, bg2, h3);

  // head (+ fused loss)
  head_kernel<<<GG, HIDN, 0, stream>>>(h1, h2, h3, batch, y, Wl1, bl1, Wl2,
                                       bl2, out, lterms, done);
}

// Round 16
// 360.314 us; speedup vs baseline: 1.0370x; 1.0370x over previous
//
#include <hip/hip_runtime.h>
#include <math.h>

#define NN 50000
#define EE 640000
#define EP (EE + NN)
#define GG 128
#define IND 128
#define LATC 32
#define HH 8
#define HLC 256
#define HIDN 128
#define SCAN_B 256
#define SCAN_G ((NN + SCAN_B - 1) / SCAN_B)  // 196
#define AGP_BLOCKS 2048

typedef unsigned short ushortT;
typedef unsigned int uintT;
typedef short bf16x8 __attribute__((ext_vector_type(8)));
typedef float f32x4 __attribute__((ext_vector_type(4)));

__device__ __forceinline__ float elu1(float v) { return v > 0.f ? v : (__expf(v) - 1.f); }

__device__ __forceinline__ ushortT f2bf(float f) {  // round-to-nearest-even
  unsigned int u = __float_as_uint(f);
  return (ushortT)((u + 0x7fffu + ((u >> 16) & 1u)) >> 16);
}
__device__ __forceinline__ float bf2f(ushortT s) {
  return __uint_as_float(((unsigned int)s) << 16);
}

// ---- CSR build ----------------------------------------------------------
__global__ void count_kernel(const int* col, int* cnt) {
  int t = blockIdx.x * blockDim.x + threadIdx.x;
  if (t < EE) atomicAdd(&cnt[col[t]], 1);
}

// hierarchical exclusive scan over (cnt[i]+1): part -> top -> final
__global__ void scan_part_kernel(const int* __restrict__ cnt,
                                 int* __restrict__ bsum) {
  int t = threadIdx.x;
  int i = blockIdx.x * SCAN_B + t;
  int v = (i < NN) ? cnt[i] + 1 : 0;  // +1 = self-loop
#pragma unroll
  for (int d = 1; d < 64; d <<= 1) v += __shfl_xor(v, d);
  __shared__ int ws[4];
  if ((t & 63) == 0) ws[t >> 6] = v;
  __syncthreads();
  if (t == 0) bsum[blockIdx.x] = ws[0] + ws[1] + ws[2] + ws[3];
}

__global__ void scan_top_kernel(const int* __restrict__ bsum,
                                int* __restrict__ ebsum,
                                int* __restrict__ offs_last) {
  int t = threadIdx.x;  // 256 threads, SCAN_G=196 values
  int v = (t < SCAN_G) ? bsum[t] : 0;
  int orig = v;
  int lane = t & 63, w = t >> 6;
#pragma unroll
  for (int d = 1; d < 64; d <<= 1) {
    int o = __shfl_up(v, d);
    if (lane >= d) v += o;
  }
  __shared__ int ws[4];
  if (lane == 63) ws[w] = v;
  __syncthreads();
  int add = 0;
  for (int j = 0; j < w; ++j) add += ws[j];
  v += add;
  if (t < SCAN_G) ebsum[t] = v - orig;   // exclusive block prefix
  if (t == SCAN_G - 1) *offs_last = v;   // total = EP
}

__global__ void scan_final_kernel(const int* __restrict__ cnt,
                                  const int* __restrict__ ebsum,
                                  int* __restrict__ offs,
                                  float* __restrict__ dinv) {
  int t = threadIdx.x;
  int i = blockIdx.x * SCAN_B + t;
  int v = (i < NN) ? cnt[i] + 1 : 0;
  int orig = v;
  int lane = t & 63, w = t >> 6;
#pragma unroll
  for (int d = 1; d < 64; d <<= 1) {
    int o = __shfl_up(v, d);
    if (lane >= d) v += o;
  }
  __shared__ int ws[4];
  if (lane == 63) ws[w] = v;
  __syncthreads();
  int add = ebsum[blockIdx.x];
  for (int j = 0; j < w; ++j) add += ws[j];
  if (i < NN) {
    offs[i] = v - orig + add;            // exclusive scan
    dinv[i] = 1.f / sqrtf((float)orig);  // deg incl. self-loop
  }
}

__global__ void build_kernel(const int* row, const int* col, const int* offs,
                             int* cursor, int* srcs) {
  int t = blockIdx.x * blockDim.x + threadIdx.x;
  if (t >= EP) return;
  int r, c;
  if (t < EE) { r = row[t]; c = col[t]; } else { r = t - EE; c = r; }
  int pos = offs[c] + atomicAdd(&cursor[c], 1);
  srcs[pos] = r;
}

// one WAVE per node: 64-wide bitonic shuffle sort (canonical order ->
// deterministic FP sums); serial fallback for deg>64 (never hit here).
__global__ void finalize_kernel(const int* offs, int* srcs) {
  int gw = (blockIdx.x * blockDim.x + threadIdx.x) >> 6;
  if (gw >= NN) return;
  int lane = threadIdx.x & 63;
  int beg = offs[gw], end = offs[gw + 1];
  int deg = end - beg;
  if (deg <= 64) {
    int v = (lane < deg) ? srcs[beg + lane] : 0x7fffffff;
    for (int k = 2; k <= 64; k <<= 1)
      for (int j = k >> 1; j > 0; j >>= 1) {
        int o = __shfl_xor(v, j);
        bool keepmin = (((lane & k) == 0) == ((lane & j) == 0));
        v = keepmin ? (v < o ? v : o) : (v > o ? v : o);
      }
    if (lane < deg) srcs[beg + lane] = v;
  } else if (lane == 0) {
    for (int i = beg + 1; i < end; ++i) {
      int v = srcs[i]; int j = i - 1;
      while (j >= beg && srcs[j] > v) { srcs[j + 1] = srcs[j]; --j; }
      srcs[j + 1] = v;
    }
  }
}

// ---- GAT1 prep: va[h*32+c] = sum_j Wg1[c][h*32+j]*asrc[h*32+j] ---------
__global__ void prep_kernel(const float* __restrict__ Wg1,
                            const float* __restrict__ asrc,
                            const float* __restrict__ adst, float* va,
                            float* vb) {
  int t = threadIdx.x;  // 256 = 8 heads x 32 c
  int c = t & 31, h = t >> 5;
  float sa = 0.f, sb = 0.f;
  for (int j = 0; j < 32; ++j) {
    float w = Wg1[(size_t)c * HLC + h * 32 + j];
    sa += w * asrc[h * 32 + j];
    sb += w * adst[h * 32 + j];
  }
  va[t] = sa;  // t = h*32+c
  vb[t] = sb;
}

// ---- x@W1: [N,128] @ [128,32], 256 rows/block, 8x4 per thread ----------
__launch_bounds__(256)
__global__ void gemm_in_kernel(const float* __restrict__ A,
                               const float* __restrict__ W,
                               float* __restrict__ out) {
  __shared__ float As[32][264];
  __shared__ float Bs[32][32];
  int bm = blockIdx.x * 256;
  int tid = threadIdx.x;
  int tx = tid & 7, ty = tid >> 3;
  float acc[8][4] = {};
  for (int k0 = 0; k0 < IND; k0 += 32) {
    {
      int gm = bm + tid;
      bool ok = gm < NN;
#pragma unroll
      for (int j = 0; j < 8; ++j) {
        float4 v = ok ? *(const float4*)(A + (size_t)gm * IND + k0 + j * 4)
                      : make_float4(0.f, 0.f, 0.f, 0.f);
        As[j * 4 + 0][tid] = v.x; As[j * 4 + 1][tid] = v.y;
        As[j * 4 + 2][tid] = v.z; As[j * 4 + 3][tid] = v.w;
      }
    }
#pragma unroll
    for (int j = 0; j < 4; ++j) {
      int idx = tid + j * 256;
      int kk = idx >> 5, c = idx & 31;
      Bs[kk][c] = W[(size_t)(k0 + kk) * LATC + c];
    }
    __syncthreads();
#pragma unroll 4
    for (int kk = 0; kk < 32; ++kk) {
      float4 a0 = *(const float4*)(&As[kk][ty * 8]);
      float4 a1 = *(const float4*)(&As[kk][ty * 8 + 4]);
      float4 b = *(const float4*)(&Bs[kk][tx * 4]);
      float ar[8] = {a0.x, a0.y, a0.z, a0.w, a1.x, a1.y, a1.z, a1.w};
      float bc[4] = {b.x, b.y, b.z, b.w};
#pragma unroll
      for (int i = 0; i < 8; ++i)
#pragma unroll
        for (int j = 0; j < 4; ++j) acc[i][j] += ar[i] * bc[j];
    }
    __syncthreads();
  }
#pragma unroll
  for (int i = 0; i < 8; ++i) {
    int gm = bm + ty * 8 + i;
    if (gm < NN)
      *(float4*)(out + (size_t)gm * LATC + tx * 4) =
          make_float4(acc[i][0], acc[i][1], acc[i][2], acc[i][3]);
  }
}

// ---- Wg2 pre-split: WhT/WlT[n][k] bf16 hi/lo (transposed) --------------
__global__ void wsplit_kernel(const float* __restrict__ Wg2,
                              ushortT* __restrict__ WhT,
                              ushortT* __restrict__ WlT) {
  int idx = blockIdx.x * 256 + threadIdx.x;
  if (idx >= HLC * HLC) return;
  int k = idx >> 8, n = idx & 255;
  float f = Wg2[idx];
  ushortT hi = f2bf(f);
  WhT[n * HLC + k] = hi;
  WlT[n * HLC + k] = f2bf(f - bf2f(hi));
}

// ---- GAT2 GEMM via split-bf16 MFMA (3 mfma ~ fp32 accuracy) ------------
__launch_bounds__(256)
__global__ void gemm_gat2_mfma(const float* __restrict__ A,
                               const ushortT* __restrict__ WhT,
                               const ushortT* __restrict__ WlT,
                               const float* __restrict__ asrc,
                               const float* __restrict__ adst,
                               ushortT* __restrict__ hgb,
                               float* __restrict__ sbuf,
                               float* __restrict__ dbuf) {
  __shared__ __align__(16) char smem[51200];
  ushortT* Ah = (ushortT*)smem;             // [64][40]
  ushortT* Al = Ah + 64 * 40;               // [64][40]  (ends at 10240B)
  ushortT* Bh = (ushortT*)(smem + 10240);   // [256][40]
  ushortT* Bl = Bh + 256 * 40;              // [256][40] (ends at 51200B)
  float* LDSf = (float*)(smem + 10240);     // overlay: [32][260] f32 (33280B)

  int tid = threadIdx.x;
  int lane = tid & 63;
  int w = tid >> 6;          // wave 0..3 -> col quadrant
  int l15 = lane & 15, lg = lane >> 4;
  int bm = blockIdx.x * 64;

  f32x4 zero4 = {0.f, 0.f, 0.f, 0.f};
  f32x4 acc[4][4];
#pragma unroll
  for (int mi = 0; mi < 4; ++mi)
#pragma unroll
    for (int ni = 0; ni < 4; ++ni) acc[mi][ni] = zero4;

  for (int k0 = 0; k0 < HLC; k0 += 32) {
    // stage A rows (fp32 -> hi/lo bf16)
    {
      int row = tid >> 2, kb = (tid & 3) * 8;
      int gm = bm + row;
      float f[8];
      if (gm < NN) {
        float4 u0 = *(const float4*)(A + (size_t)gm * HLC + k0 + kb);
        float4 u1 = *(const float4*)(A + (size_t)gm * HLC + k0 + kb + 4);
        f[0] = u0.x; f[1] = u0.y; f[2] = u0.z; f[3] = u0.w;
        f[4] = u1.x; f[5] = u1.y; f[6] = u1.z; f[7] = u1.w;
      } else {
#pragma unroll
        for (int j = 0; j < 8; ++j) f[j] = 0.f;
      }
      bf16x8 vh, vl;
#pragma unroll
      for (int j = 0; j < 8; ++j) {
        ushortT hi = f2bf(f[j]);
        vh[j] = (short)hi;
        vl[j] = (short)f2bf(f[j] - bf2f(hi));
      }
      *(bf16x8*)(Ah + row * 40 + kb) = vh;
      *(bf16x8*)(Al + row * 40 + kb) = vl;
    }
    // stage B slice from pre-split WhT/WlT (n = tid, 32 consecutive k)
    {
      const bf16x8* ph = (const bf16x8*)(WhT + (size_t)tid * HLC + k0);
      const bf16x8* pl = (const bf16x8*)(WlT + (size_t)tid * HLC + k0);
#pragma unroll
      for (int i = 0; i < 4; ++i) {
        *(bf16x8*)(Bh + tid * 40 + i * 8) = ph[i];
        *(bf16x8*)(Bl + tid * 40 + i * 8) = pl[i];
      }
    }
    __syncthreads();
    bf16x8 ah[4], al[4], bh[4], bl[4];
#pragma unroll
    for (int mi = 0; mi < 4; ++mi) {
      int off = (mi * 16 + l15) * 40 + lg * 8;
      ah[mi] = *(const bf16x8*)(Ah + off);
      al[mi] = *(const bf16x8*)(Al + off);
    }
#pragma unroll
    for (int ni = 0; ni < 4; ++ni) {
      int off = (w * 64 + ni * 16 + l15) * 40 + lg * 8;
      bh[ni] = *(const bf16x8*)(Bh + off);
      bl[ni] = *(const bf16x8*)(Bl + off);
    }
#pragma unroll
    for (int mi = 0; mi < 4; ++mi)
#pragma unroll
      for (int ni = 0; ni < 4; ++ni) {
        acc[mi][ni] = __builtin_amdgcn_mfma_f32_16x16x32_bf16(
            al[mi], bh[ni], acc[mi][ni], 0, 0, 0);
        acc[mi][ni] = __builtin_amdgcn_mfma_f32_16x16x32_bf16(
            ah[mi], bl[ni], acc[mi][ni], 0, 0, 0);
        acc[mi][ni] = __builtin_amdgcn_mfma_f32_16x16x32_bf16(
            ah[mi], bh[ni], acc[mi][ni], 0, 0, 0);
      }
    __syncthreads();
  }

  // ---- s/d epilogue from fp32 acc (exact logits) ----
  float av[4], bv[4];
#pragma unroll
  for (int ni = 0; ni < 4; ++ni) {
    int c = w * 64 + ni * 16 + l15;
    av[ni] = asrc[c];
    bv[ni] = adst[c];
  }
#pragma unroll
  for (int mi = 0; mi < 4; ++mi)
#pragma unroll
    for (int r = 0; r < 4; ++r) {
      int gm = bm + mi * 16 + lg * 4 + r;
      float s0 = acc[mi][0][r] * av[0] + acc[mi][1][r] * av[1];
      float s1 = acc[mi][2][r] * av[2] + acc[mi][3][r] * av[3];
      float d0 = acc[mi][0][r] * bv[0] + acc[mi][1][r] * bv[1];
      float d1 = acc[mi][2][r] * bv[2] + acc[mi][3][r] * bv[3];
#pragma unroll
      for (int m = 1; m <= 8; m <<= 1) {
        s0 += __shfl_xor(s0, m);
        s1 += __shfl_xor(s1, m);
        d0 += __shfl_xor(d0, m);
        d1 += __shfl_xor(d1, m);
      }
      if (l15 == 0 && gm < NN) {
        sbuf[gm * HH + 2 * w] = s0;
        sbuf[gm * HH + 2 * w + 1] = s1;
        dbuf[gm * HH + 2 * w] = d0;
        dbuf[gm * HH + 2 * w + 1] = d1;
      }
    }

  // ---- hg bf16 store via LDS repack (two 32-row passes) ----
#pragma unroll
  for (int p = 0; p < 2; ++p) {
    __syncthreads();
#pragma unroll
    for (int q = 0; q < 2; ++q) {
      int mi = 2 * p + q;
#pragma unroll
      for (int ni = 0; ni < 4; ++ni)
#pragma unroll
        for (int r = 0; r < 4; ++r) {
          int lrow = q * 16 + lg * 4 + r;
          LDSf[lrow * 260 + w * 64 + ni * 16 + l15] = acc[mi][ni][r];
        }
    }
    __syncthreads();
    int row = tid >> 3, cb = (tid & 7) * 32;
    int gm = bm + p * 32 + row;
    if (gm < NN) {
      uintT u[16];
#pragma unroll
      for (int i = 0; i < 8; ++i) {
        float4 v = *(const float4*)(LDSf + row * 260 + cb + i * 4);
        u[2 * i] = (uintT)f2bf(v.x) | ((uintT)f2bf(v.y) << 16);
        u[2 * i + 1] = (uintT)f2bf(v.z) | ((uintT)f2bf(v.w) << 16);
      }
      uintT* dst = (uintT*)(hgb + (size_t)gm * HLC + cb);
#pragma unroll
      for (int i = 0; i < 4; ++i) {
        uint4 s;
        s.x = u[4 * i]; s.y = u[4 * i + 1];
        s.z = u[4 * i + 2]; s.w = u[4 * i + 3];
        *(uint4*)(dst + 4 * i) = s;
      }
    }
  }
}

// ---- FUSED GCN aggregate + GAT1 s/d logits (va/vb precomputed) ---------
__global__ void gcn_agg_sd_kernel(const float* __restrict__ hW,
                                  const int* offs, const int* srcs,
                                  const float* dinv, const float* b1,
                                  const float* __restrict__ vag,
                                  const float* __restrict__ vbg,
                                  float* h1, float* s, float* d) {
  __shared__ float va[HLC], vb[HLC];
  __shared__ float rowbuf[4][LATC];
  int t = threadIdx.x;
  va[t] = vag[t];  // coalesced 2KB stage
  vb[t] = vbg[t];
  __syncthreads();
  int wid = (blockIdx.x * blockDim.x + t) >> 6;
  int lane = t & 63;
  int wv = t >> 6;
  int c = lane & 31, half = lane >> 5;
  int beg = offs[wid], end = offs[wid + 1];
  float acc = 0.f;
  for (int p = beg + half; p < end; p += 2) {
    int src = srcs[p];
    acc += dinv[src] * hW[src * LATC + c];
  }
  acc += __shfl_xor(acc, 32);
  if (lane < 32) {
    float v = elu1(dinv[wid] * acc + b1[c]);
    h1[wid * LATC + c] = v;
    rowbuf[wv][c] = v;  // same-wave LDS: no barrier needed
  }
  int h = lane >> 3, k = lane & 7;
  float ps = 0.f, pd = 0.f;
#pragma unroll
  for (int j = 0; j < 4; ++j) {
    float x = rowbuf[wv][k * 4 + j];
    ps += x * va[h * 32 + k * 4 + j];
    pd += x * vb[h * 32 + k * 4 + j];
  }
  ps += __shfl_xor(ps, 1); pd += __shfl_xor(pd, 1);
  ps += __shfl_xor(ps, 2); pd += __shfl_xor(pd, 2);
  ps += __shfl_xor(ps, 4); pd += __shfl_xor(pd, 4);
  if (k == 0) {
    s[wid * HH + h] = ps;
    d[wid * HH + h] = pd;
  }
}

// ---- FUSED GAT1 aggregate + projection + bias + ELU --------------------
// Per-wave, barrier-free (R13 structure). aggs stride 33: proj reads
// aggs[wv][hq*33+cc] put the 8 head-groups on 8 DISTINCT banks (stride 32
// was an 8-way conflict on every proj read -> 2.0M conflict cycles).
__launch_bounds__(256)
__global__ void gat1_aggproj_kernel(const float* __restrict__ h1,
                                    const float* __restrict__ s,
                                    const float* __restrict__ d,
                                    const int* offs, const int* srcs,
                                    const float* __restrict__ Wg1,
                                    const float* __restrict__ bg,
                                    float* __restrict__ h2) {
  __shared__ float Ws[32][HLC];   // 32 KB
  __shared__ float aggs[4][264];  // stride-33 heads -> bank-clean
  int t = threadIdx.x;
  {
    const float4* Wv = (const float4*)Wg1;
    float4* Bv = (float4*)Ws;
#pragma unroll
    for (int i = 0; i < 8; ++i) Bv[t + i * 256] = Wv[t + i * 256];
  }
  __syncthreads();
  int lane = t & 63;
  int wv = t >> 6;
  int g = lane >> 5, l5 = lane & 31;
  int h = l5 >> 2, c8 = (l5 & 3) * 8;
  int qb = lane * 4, hq = lane >> 3;
  float4 bb = *(const float4*)(bg + qb);
  for (int wid = blockIdx.x * 4 + wv; wid < NN; wid += AGP_BLOCKS * 4) {
    int beg = offs[wid], end = offs[wid + 1];
    float dn = d[wid * HH + h];
    float self = s[wid * HH + h] + dn;
    float m = self > 0.f ? self : 0.2f * self;  // self-loop always present
    float z = 0.f;
    float a[8] = {};
#pragma unroll 2
    for (int p = beg + g; p < end; p += 2) {
      int src = srcs[p];
      float sv = s[src * HH + h] + dn;
      float logit = sv > 0.f ? sv : 0.2f * sv;
      float e = __expf(logit - m);
      z += e;
      float4 v0 = *(const float4*)(h1 + (size_t)src * LATC + c8);
      float4 v1 = *(const float4*)(h1 + (size_t)src * LATC + c8 + 4);
      a[0] += e * v0.x; a[1] += e * v0.y; a[2] += e * v0.z; a[3] += e * v0.w;
      a[4] += e * v1.x; a[5] += e * v1.y; a[6] += e * v1.z; a[7] += e * v1.w;
    }
    z += __shfl_xor(z, 32);
#pragma unroll
    for (int j = 0; j < 8; ++j) a[j] += __shfl_xor(a[j], 32);
    float zinv = 1.f / (z + 1e-16f);
    if (g == 0) {
#pragma unroll
      for (int j = 0; j < 8; ++j)
        aggs[wv][h * 33 + c8 + j] = a[j] * zinv;  // same-wave LDS use
    }
    // projection: out[q] = sum_c agg[hq*33+c] * Wg1[c][q], q = qb..qb+3
    float o0 = bb.x, o1 = bb.y, o2 = bb.z, o3 = bb.w;
#pragma unroll 8
    for (int cc = 0; cc < 32; ++cc) {
      float av = aggs[wv][hq * 33 + cc];  // broadcast within head group
      float4 w4 = *(const float4*)(&Ws[cc][qb]);
      o0 += av * w4.x; o1 += av * w4.y; o2 += av * w4.z; o3 += av * w4.w;
    }
    *(float4*)(h2 + (size_t)wid * HLC + qb) =
        make_float4(elu1(o0), elu1(o1), elu1(o2), elu1(o3));
  }
}

// ---- GAT2 aggregate: bf16 hg gather, one wave per node -----------------
__global__ void gat_agg_kernel(const ushortT* __restrict__ hgb,
                               const float* __restrict__ s,
                               const float* __restrict__ dd, const int* offs,
                               const int* srcs, const float* bg, float* out) {
  int wid = (blockIdx.x * blockDim.x + threadIdx.x) >> 6;
  if (wid >= NN) return;
  int lane = threadIdx.x & 63;
  int hh = lane >> 3;
  int ch = lane << 2;
  int beg = offs[wid], end = offs[wid + 1];
  float dn = dd[wid * HH + hh];
  float self = s[wid * HH + hh] + dn;
  float m = self > 0.f ? self : 0.2f * self;
  float z = 0.f;
  float ax = 0.f, ay = 0.f, az = 0.f, aw = 0.f;
#pragma unroll 4
  for (int p = beg; p < end; ++p) {
    int src = srcs[p];
    float xv = s[src * HH + hh] + dn;
    float logit = xv > 0.f ? xv : 0.2f * xv;
    float e = __expf(logit - m);
    z += e;
    ushort4 v = *(const ushort4*)(hgb + (size_t)src * HLC + ch);
    ax += e * bf2f(v.x); ay += e * bf2f(v.y);
    az += e * bf2f(v.z); aw += e * bf2f(v.w);
  }
  float zinv = 1.f / (z + 1e-16f);
  float4 bb = *(const float4*)(bg + ch);
  float4 o;
  o.x = elu1(ax * zinv + bb.x); o.y = elu1(ay * zinv + bb.y);
  o.z = elu1(az * zinv + bb.z); o.w = elu1(aw * zinv + bb.w);
  *(float4*)(out + (size_t)wid * HLC + ch) = o;
}

// ---- readout head + fused loss (last-block ticket) ---------------------
__global__ void head_kernel(const float* __restrict__ h1,
                            const float* __restrict__ h2,
                            const float* __restrict__ h3, const int* batch,
                            const int* y, const float* __restrict__ Wl1,
                            const float* bl1, const float* __restrict__ Wl2,
                            const float* bl2, float* out, float* lterms,
                            int* done) {
  int g = blockIdx.x, tid = threadIdx.x;
  __shared__ float cat[544];
  __shared__ float hidden[HIDN];
  __shared__ float raw_s[2];
  __shared__ int idx_s;
  if (tid == 0) {
    int lo = 0, hi = NN;
    while (lo < hi) { int mid = (lo + hi) >> 1; if (batch[mid] < g) lo = mid + 1; else hi = mid; }
    idx_s = lo;
  }
  __syncthreads();
  int idx = idx_s;
  if (tid < 32) cat[tid] = h1[idx * LATC + tid];
  for (int i = tid; i < HLC; i += HIDN) {
    cat[32 + i] = h2[(size_t)idx * HLC + i];
    cat[288 + i] = h3[(size_t)idx * HLC + i];
  }
  __syncthreads();
  float f = bl1[tid];
  for (int k = 0; k < 544; ++k) f += cat[k] * Wl1[k * HIDN + tid];
  out[641 + g * HIDN + tid] = f;
  hidden[tid] = elu1(f);
  __syncthreads();
  if (tid < 2) {
    float r = bl2[tid];
    for (int j = 0; j < HIDN; ++j) r += hidden[j] * Wl2[j * 2 + tid];
    raw_s[tid] = r;
  }
  __syncthreads();
  if (tid == 0) {
    float r0 = raw_s[0], r1 = raw_s[1];
    float mx = fmaxf(r0, r1);
    float e0 = expf(r0 - mx), e1 = expf(r1 - mx);
    float zz = e0 + e1;
    float lse = mx + logf(zz);
    float lg0 = r0 - lse, lg1 = r1 - lse;
    out[g * 2 + 0] = lg0; out[g * 2 + 1] = lg1;
    out[385 + g * 2 + 0] = e0 / zz; out[385 + g * 2 + 1] = e1 / zz;
    out[257 + g] = (r1 > r0) ? 1.f : 0.f;
    lterms[g] = -((y[g] == 0) ? lg0 : lg1);
    __threadfence();
    int ticket = atomicAdd(done, 1);
    if (ticket == GG - 1) {  // last graph: deterministic fixed-order sum
      __threadfence();
      float sum = 0.f;
      for (int j = 0; j < GG; ++j) sum += lterms[j];
      out[256] = sum / (float)GG;
    }
  }
}

// ------------------------------------------------------------------------
extern "C" void kernel_launch(void* const* d_in, const int* in_sizes, int n_in,
                              void* d_out, int out_size, void* d_ws,
                              size_t ws_size, hipStream_t stream) {
  const float* x = (const float*)d_in[0];
  const int* ei = (const int*)d_in[1];
  const int* batch = (const int*)d_in[2];
  const int* y = (const int*)d_in[3];
  const float* W1 = (const float*)d_in[4];
  const float* b1 = (const float*)d_in[5];
  const float* Wg1 = (const float*)d_in[6];
  const float* asrc1 = (const float*)d_in[7];
  const float* adst1 = (const float*)d_in[8];
  const float* bg1 = (const float*)d_in[9];
  const float* Wg2 = (const float*)d_in[10];
  const float* asrc2 = (const float*)d_in[11];
  const float* adst2 = (const float*)d_in[12];
  const float* bg2 = (const float*)d_in[13];
  const float* Wl1 = (const float*)d_in[14];
  const float* bl1 = (const float*)d_in[15];
  const float* Wl2 = (const float*)d_in[16];
  const float* bl2 = (const float*)d_in[17];
  float* out = (float*)d_out;

  const int* erow = ei;
  const int* ecol = ei + EE;

  char* p = (char*)d_ws;
  auto alloc = [&](size_t bytes) {
    void* r = (void*)p;
    p += (bytes + 255) & ~(size_t)255;
    return r;
  };
  int* cntcur = (int*)alloc(((size_t)2 * NN + 64) * 4);  // cnt|cursor|done
  int* cnt = cntcur;
  int* cursor = cntcur + NN;
  int* done = cntcur + 2 * NN;
  int* offs = (int*)alloc((NN + 1) * 4);
  int* srcs = (int*)alloc((size_t)EP * 4);
  int* bsum = (int*)alloc(SCAN_G * 4);
  int* ebsum = (int*)alloc(SCAN_G * 4);
  float* dinv = (float*)alloc(NN * 4);
  float* hW = (float*)alloc((size_t)NN * LATC * 4);
  float* h1 = (float*)alloc((size_t)NN * LATC * 4);
  float* hg = (float*)alloc((size_t)NN * HLC * 4);  // hgb (bf16) backing
  float* h2 = (float*)alloc((size_t)NN * HLC * 4);
  float* h3 = (float*)alloc((size_t)NN * HLC * 4);
  float* sbuf = (float*)alloc((size_t)NN * HH * 4);
  float* dbuf = (float*)alloc((size_t)NN * HH * 4);
  float* va = (float*)alloc(HLC * 4);
  float* vb = (float*)alloc(HLC * 4);
  float* lterms = (float*)alloc(GG * 4);
  ushortT* whT = (ushortT*)alloc((size_t)HLC * HLC * 2);
  ushortT* wlT = (ushortT*)alloc((size_t)HLC * HLC * 2);
  ushortT* hgb = (ushortT*)hg;

  const int NBLK = (NN + 63) / 64;  // 782

  // CSR (reused by all three conv layers)
  hipMemsetAsync(cntcur, 0, ((size_t)2 * NN + 64) * 4, stream);
  count_kernel<<<(EE + 255) / 256, 256, 0, stream>>>(ecol, cnt);
  scan_part_kernel<<<SCAN_G, SCAN_B, 0, stream>>>(cnt, bsum);
  scan_top_kernel<<<1, 256, 0, stream>>>(bsum, ebsum, offs + NN);
  scan_final_kernel<<<SCAN_G, SCAN_B, 0, stream>>>(cnt, ebsum, offs, dinv);
  build_kernel<<<(EP + 255) / 256, 256, 0, stream>>>(erow, ecol, offs, cursor, srcs);
  finalize_kernel<<<(NN + 3) / 4, 256, 0, stream>>>(offs, srcs);

  // independent weight prep
  wsplit_kernel<<<(HLC * HLC + 255) / 256, 256, 0, stream>>>(Wg2, whT, wlT);
  prep_kernel<<<1, 256, 0, stream>>>(Wg1, asrc1, adst1, va, vb);

  // GCN (+ fused GAT1 s/d logits, va/vb from global)
  gemm_in_kernel<<<(NN + 255) / 256, 256, 0, stream>>>(x, W1, hW);
  gcn_agg_sd_kernel<<<(NN + 3) / 4, 256, 0, stream>>>(
      hW, offs, srcs, dinv, b1, va, vb, h1, sbuf, dbuf);

  // GAT 1 — fused gather + projection (per-wave, bank-clean aggs)
  gat1_aggproj_kernel<<<AGP_BLOCKS, 256, 0, stream>>>(h1, sbuf, dbuf, offs,
                                                      srcs, Wg1, bg1, h2);

  // GAT 2 — split-bf16 MFMA GEMM + exact s/d epilogue + bf16 hg
  gemm_gat2_mfma<<<NBLK, 256, 0, stream>>>(h2, whT, wlT, asrc2, adst2, hgb,
                                           sbuf, dbuf);
  gat_agg_kernel<<<(NN + 3) / 4, 256, 0, stream>>>(hgb, sbuf, dbuf, offs, srcs, bg2, h3);

  // head (+ fused loss)
  head_kernel<<<GG, HIDN, 0, stream>>>(h1, h2, h3, batch, y, Wl1, bl1, Wl2,
                                       bl2, out, lterms, done);
}

// Round 17
// 356.566 us; speedup vs baseline: 1.0479x; 1.0105x over previous
//
#include <hip/hip_runtime.h>
#include <math.h>

#define NN 50000
#define EE 640000
#define EP (EE + NN)
#define GG 128
#define IND 128
#define LATC 32
#define HH 8
#define HLC 256
#define HIDN 128
#define SCAN_B 256
#define SCAN_G ((NN + SCAN_B - 1) / SCAN_B)  // 196
#define AGP_BLOCKS 2048

typedef unsigned short ushortT;
typedef unsigned int uintT;
typedef short bf16x8 __attribute__((ext_vector_type(8)));
typedef float f32x4 __attribute__((ext_vector_type(4)));

__device__ __forceinline__ float elu1(float v) { return v > 0.f ? v : (__expf(v) - 1.f); }

__device__ __forceinline__ ushortT f2bf(float f) {  // round-to-nearest-even
  unsigned int u = __float_as_uint(f);
  return (ushortT)((u + 0x7fffu + ((u >> 16) & 1u)) >> 16);
}
__device__ __forceinline__ float bf2f(ushortT s) {
  return __uint_as_float(((unsigned int)s) << 16);
}

// ---- CSR build ----------------------------------------------------------
__global__ void count_kernel(const int* col, int* cnt) {
  int t = blockIdx.x * blockDim.x + threadIdx.x;
  if (t < EE) atomicAdd(&cnt[col[t]], 1);
}

// hierarchical exclusive scan over (cnt[i]+1): part -> top -> final
__global__ void scan_part_kernel(const int* __restrict__ cnt,
                                 int* __restrict__ bsum) {
  int t = threadIdx.x;
  int i = blockIdx.x * SCAN_B + t;
  int v = (i < NN) ? cnt[i] + 1 : 0;  // +1 = self-loop
#pragma unroll
  for (int d = 1; d < 64; d <<= 1) v += __shfl_xor(v, d);
  __shared__ int ws[4];
  if ((t & 63) == 0) ws[t >> 6] = v;
  __syncthreads();
  if (t == 0) bsum[blockIdx.x] = ws[0] + ws[1] + ws[2] + ws[3];
}

__global__ void scan_top_kernel(const int* __restrict__ bsum,
                                int* __restrict__ ebsum,
                                int* __restrict__ offs_last) {
  int t = threadIdx.x;  // 256 threads, SCAN_G=196 values
  int v = (t < SCAN_G) ? bsum[t] : 0;
  int orig = v;
  int lane = t & 63, w = t >> 6;
#pragma unroll
  for (int d = 1; d < 64; d <<= 1) {
    int o = __shfl_up(v, d);
    if (lane >= d) v += o;
  }
  __shared__ int ws[4];
  if (lane == 63) ws[w] = v;
  __syncthreads();
  int add = 0;
  for (int j = 0; j < w; ++j) add += ws[j];
  v += add;
  if (t < SCAN_G) ebsum[t] = v - orig;   // exclusive block prefix
  if (t == SCAN_G - 1) *offs_last = v;   // total = EP
}

__global__ void scan_final_kernel(const int* __restrict__ cnt,
                                  const int* __restrict__ ebsum,
                                  int* __restrict__ offs,
                                  float* __restrict__ dinv) {
  int t = threadIdx.x;
  int i = blockIdx.x * SCAN_B + t;
  int v = (i < NN) ? cnt[i] + 1 : 0;
  int orig = v;
  int lane = t & 63, w = t >> 6;
#pragma unroll
  for (int d = 1; d < 64; d <<= 1) {
    int o = __shfl_up(v, d);
    if (lane >= d) v += o;
  }
  __shared__ int ws[4];
  if (lane == 63) ws[w] = v;
  __syncthreads();
  int add = ebsum[blockIdx.x];
  for (int j = 0; j < w; ++j) add += ws[j];
  if (i < NN) {
    offs[i] = v - orig + add;            // exclusive scan
    dinv[i] = 1.f / sqrtf((float)orig);  // deg incl. self-loop
  }
}

__global__ void build_kernel(const int* row, const int* col, const int* offs,
                             int* cursor, int* srcs) {
  int t = blockIdx.x * blockDim.x + threadIdx.x;
  if (t >= EP) return;
  int r, c;
  if (t < EE) { r = row[t]; c = col[t]; } else { r = t - EE; c = r; }
  int pos = offs[c] + atomicAdd(&cursor[c], 1);
  srcs[pos] = r;
}

// one WAVE per node: 64-wide bitonic shuffle sort (canonical order ->
// deterministic FP sums); serial fallback for deg>64 (never hit here).
__global__ void finalize_kernel(const int* offs, int* srcs) {
  int gw = (blockIdx.x * blockDim.x + threadIdx.x) >> 6;
  if (gw >= NN) return;
  int lane = threadIdx.x & 63;
  int beg = offs[gw], end = offs[gw + 1];
  int deg = end - beg;
  if (deg <= 64) {
    int v = (lane < deg) ? srcs[beg + lane] : 0x7fffffff;
    for (int k = 2; k <= 64; k <<= 1)
      for (int j = k >> 1; j > 0; j >>= 1) {
        int o = __shfl_xor(v, j);
        bool keepmin = (((lane & k) == 0) == ((lane & j) == 0));
        v = keepmin ? (v < o ? v : o) : (v > o ? v : o);
      }
    if (lane < deg) srcs[beg + lane] = v;
  } else if (lane == 0) {
    for (int i = beg + 1; i < end; ++i) {
      int v = srcs[i]; int j = i - 1;
      while (j >= beg && srcs[j] > v) { srcs[j + 1] = srcs[j]; --j; }
      srcs[j + 1] = v;
    }
  }
}

// ---- GAT1 prep: va[h*32+c] = sum_j Wg1[c][h*32+j]*asrc[h*32+j] ---------
__global__ void prep_kernel(const float* __restrict__ Wg1,
                            const float* __restrict__ asrc,
                            const float* __restrict__ adst, float* va,
                            float* vb) {
  int t = threadIdx.x;  // 256 = 8 heads x 32 c
  int c = t & 31, h = t >> 5;
  float sa = 0.f, sb = 0.f;
  for (int j = 0; j < 32; ++j) {
    float w = Wg1[(size_t)c * HLC + h * 32 + j];
    sa += w * asrc[h * 32 + j];
    sb += w * adst[h * 32 + j];
  }
  va[t] = sa;  // t = h*32+c
  vb[t] = sb;
}

// ---- x@W1: [N,128] @ [128,32], 256 rows/block, 8x4 per thread ----------
__launch_bounds__(256)
__global__ void gemm_in_kernel(const float* __restrict__ A,
                               const float* __restrict__ W,
                               float* __restrict__ out) {
  __shared__ float As[32][264];
  __shared__ float Bs[32][32];
  int bm = blockIdx.x * 256;
  int tid = threadIdx.x;
  int tx = tid & 7, ty = tid >> 3;
  float acc[8][4] = {};
  for (int k0 = 0; k0 < IND; k0 += 32) {
    {
      int gm = bm + tid;
      bool ok = gm < NN;
#pragma unroll
      for (int j = 0; j < 8; ++j) {
        float4 v = ok ? *(const float4*)(A + (size_t)gm * IND + k0 + j * 4)
                      : make_float4(0.f, 0.f, 0.f, 0.f);
        As[j * 4 + 0][tid] = v.x; As[j * 4 + 1][tid] = v.y;
        As[j * 4 + 2][tid] = v.z; As[j * 4 + 3][tid] = v.w;
      }
    }
#pragma unroll
    for (int j = 0; j < 4; ++j) {
      int idx = tid + j * 256;
      int kk = idx >> 5, c = idx & 31;
      Bs[kk][c] = W[(size_t)(k0 + kk) * LATC + c];
    }
    __syncthreads();
#pragma unroll 4
    for (int kk = 0; kk < 32; ++kk) {
      float4 a0 = *(const float4*)(&As[kk][ty * 8]);
      float4 a1 = *(const float4*)(&As[kk][ty * 8 + 4]);
      float4 b = *(const float4*)(&Bs[kk][tx * 4]);
      float ar[8] = {a0.x, a0.y, a0.z, a0.w, a1.x, a1.y, a1.z, a1.w};
      float bc[4] = {b.x, b.y, b.z, b.w};
#pragma unroll
      for (int i = 0; i < 8; ++i)
#pragma unroll
        for (int j = 0; j < 4; ++j) acc[i][j] += ar[i] * bc[j];
    }
    __syncthreads();
  }
#pragma unroll
  for (int i = 0; i < 8; ++i) {
    int gm = bm + ty * 8 + i;
    if (gm < NN)
      *(float4*)(out + (size_t)gm * LATC + tx * 4) =
          make_float4(acc[i][0], acc[i][1], acc[i][2], acc[i][3]);
  }
}

// ---- Wg2 pre-split: WhT/WlT[n][k] bf16 hi/lo (transposed) --------------
__global__ void wsplit_kernel(const float* __restrict__ Wg2,
                              ushortT* __restrict__ WhT,
                              ushortT* __restrict__ WlT) {
  int idx = blockIdx.x * 256 + threadIdx.x;
  if (idx >= HLC * HLC) return;
  int k = idx >> 8, n = idx & 255;
  float f = Wg2[idx];
  ushortT hi = f2bf(f);
  WhT[n * HLC + k] = hi;
  WlT[n * HLC + k] = f2bf(f - bf2f(hi));
}

// ---- GAT2 GEMM via split-bf16 MFMA (3 mfma ~ fp32 accuracy) ------------
__launch_bounds__(256)
__global__ void gemm_gat2_mfma(const float* __restrict__ A,
                               const ushortT* __restrict__ WhT,
                               const ushortT* __restrict__ WlT,
                               const float* __restrict__ asrc,
                               const float* __restrict__ adst,
                               ushortT* __restrict__ hgb,
                               float* __restrict__ sbuf,
                               float* __restrict__ dbuf) {
  __shared__ __align__(16) char smem[51200];
  ushortT* Ah = (ushortT*)smem;             // [64][40]
  ushortT* Al = Ah + 64 * 40;               // [64][40]  (ends at 10240B)
  ushortT* Bh = (ushortT*)(smem + 10240);   // [256][40]
  ushortT* Bl = Bh + 256 * 40;              // [256][40] (ends at 51200B)
  float* LDSf = (float*)(smem + 10240);     // overlay: [32][260] f32 (33280B)

  int tid = threadIdx.x;
  int lane = tid & 63;
  int w = tid >> 6;          // wave 0..3 -> col quadrant
  int l15 = lane & 15, lg = lane >> 4;
  int bm = blockIdx.x * 64;

  f32x4 zero4 = {0.f, 0.f, 0.f, 0.f};
  f32x4 acc[4][4];
#pragma unroll
  for (int mi = 0; mi < 4; ++mi)
#pragma unroll
    for (int ni = 0; ni < 4; ++ni) acc[mi][ni] = zero4;

  for (int k0 = 0; k0 < HLC; k0 += 32) {
    // stage A rows (fp32 -> hi/lo bf16)
    {
      int row = tid >> 2, kb = (tid & 3) * 8;
      int gm = bm + row;
      float f[8];
      if (gm < NN) {
        float4 u0 = *(const float4*)(A + (size_t)gm * HLC + k0 + kb);
        float4 u1 = *(const float4*)(A + (size_t)gm * HLC + k0 + kb + 4);
        f[0] = u0.x; f[1] = u0.y; f[2] = u0.z; f[3] = u0.w;
        f[4] = u1.x; f[5] = u1.y; f[6] = u1.z; f[7] = u1.w;
      } else {
#pragma unroll
        for (int j = 0; j < 8; ++j) f[j] = 0.f;
      }
      bf16x8 vh, vl;
#pragma unroll
      for (int j = 0; j < 8; ++j) {
        ushortT hi = f2bf(f[j]);
        vh[j] = (short)hi;
        vl[j] = (short)f2bf(f[j] - bf2f(hi));
      }
      *(bf16x8*)(Ah + row * 40 + kb) = vh;
      *(bf16x8*)(Al + row * 40 + kb) = vl;
    }
    // stage B slice from pre-split WhT/WlT (n = tid, 32 consecutive k)
    {
      const bf16x8* ph = (const bf16x8*)(WhT + (size_t)tid * HLC + k0);
      const bf16x8* pl = (const bf16x8*)(WlT + (size_t)tid * HLC + k0);
#pragma unroll
      for (int i = 0; i < 4; ++i) {
        *(bf16x8*)(Bh + tid * 40 + i * 8) = ph[i];
        *(bf16x8*)(Bl + tid * 40 + i * 8) = pl[i];
      }
    }
    __syncthreads();
    bf16x8 ah[4], al[4], bh[4], bl[4];
#pragma unroll
    for (int mi = 0; mi < 4; ++mi) {
      int off = (mi * 16 + l15) * 40 + lg * 8;
      ah[mi] = *(const bf16x8*)(Ah + off);
      al[mi] = *(const bf16x8*)(Al + off);
    }
#pragma unroll
    for (int ni = 0; ni < 4; ++ni) {
      int off = (w * 64 + ni * 16 + l15) * 40 + lg * 8;
      bh[ni] = *(const bf16x8*)(Bh + off);
      bl[ni] = *(const bf16x8*)(Bl + off);
    }
#pragma unroll
    for (int mi = 0; mi < 4; ++mi)
#pragma unroll
      for (int ni = 0; ni < 4; ++ni) {
        acc[mi][ni] = __builtin_amdgcn_mfma_f32_16x16x32_bf16(
            al[mi], bh[ni], acc[mi][ni], 0, 0, 0);
        acc[mi][ni] = __builtin_amdgcn_mfma_f32_16x16x32_bf16(
            ah[mi], bl[ni], acc[mi][ni], 0, 0, 0);
        acc[mi][ni] = __builtin_amdgcn_mfma_f32_16x16x32_bf16(
            ah[mi], bh[ni], acc[mi][ni], 0, 0, 0);
      }
    __syncthreads();
  }

  // ---- s/d epilogue from fp32 acc (exact logits) ----
  float av[4], bv[4];
#pragma unroll
  for (int ni = 0; ni < 4; ++ni) {
    int c = w * 64 + ni * 16 + l15;
    av[ni] = asrc[c];
    bv[ni] = adst[c];
  }
#pragma unroll
  for (int mi = 0; mi < 4; ++mi)
#pragma unroll
    for (int r = 0; r < 4; ++r) {
      int gm = bm + mi * 16 + lg * 4 + r;
      float s0 = acc[mi][0][r] * av[0] + acc[mi][1][r] * av[1];
      float s1 = acc[mi][2][r] * av[2] + acc[mi][3][r] * av[3];
      float d0 = acc[mi][0][r] * bv[0] + acc[mi][1][r] * bv[1];
      float d1 = acc[mi][2][r] * bv[2] + acc[mi][3][r] * bv[3];
#pragma unroll
      for (int m = 1; m <= 8; m <<= 1) {
        s0 += __shfl_xor(s0, m);
        s1 += __shfl_xor(s1, m);
        d0 += __shfl_xor(d0, m);
        d1 += __shfl_xor(d1, m);
      }
      if (l15 == 0 && gm < NN) {
        sbuf[gm * HH + 2 * w] = s0;
        sbuf[gm * HH + 2 * w + 1] = s1;
        dbuf[gm * HH + 2 * w] = d0;
        dbuf[gm * HH + 2 * w + 1] = d1;
      }
    }

  // ---- hg bf16 store via LDS repack (two 32-row passes) ----
#pragma unroll
  for (int p = 0; p < 2; ++p) {
    __syncthreads();
#pragma unroll
    for (int q = 0; q < 2; ++q) {
      int mi = 2 * p + q;
#pragma unroll
      for (int ni = 0; ni < 4; ++ni)
#pragma unroll
        for (int r = 0; r < 4; ++r) {
          int lrow = q * 16 + lg * 4 + r;
          LDSf[lrow * 260 + w * 64 + ni * 16 + l15] = acc[mi][ni][r];
        }
    }
    __syncthreads();
    int row = tid >> 3, cb = (tid & 7) * 32;
    int gm = bm + p * 32 + row;
    if (gm < NN) {
      uintT u[16];
#pragma unroll
      for (int i = 0; i < 8; ++i) {
        float4 v = *(const float4*)(LDSf + row * 260 + cb + i * 4);
        u[2 * i] = (uintT)f2bf(v.x) | ((uintT)f2bf(v.y) << 16);
        u[2 * i + 1] = (uintT)f2bf(v.z) | ((uintT)f2bf(v.w) << 16);
      }
      uintT* dst = (uintT*)(hgb + (size_t)gm * HLC + cb);
#pragma unroll
      for (int i = 0; i < 4; ++i) {
        uint4 s;
        s.x = u[4 * i]; s.y = u[4 * i + 1];
        s.z = u[4 * i + 2]; s.w = u[4 * i + 3];
        *(uint4*)(dst + 4 * i) = s;
      }
    }
  }
}

// ---- FUSED GCN aggregate + GAT1 s/d logits (va/vb precomputed) ---------
__global__ void gcn_agg_sd_kernel(const float* __restrict__ hW,
                                  const int* offs, const int* srcs,
                                  const float* dinv, const float* b1,
                                  const float* __restrict__ vag,
                                  const float* __restrict__ vbg,
                                  float* h1, float* s, float* d) {
  __shared__ float va[HLC], vb[HLC];
  __shared__ float rowbuf[4][LATC];
  int t = threadIdx.x;
  va[t] = vag[t];  // coalesced 2KB stage
  vb[t] = vbg[t];
  __syncthreads();
  int wid = (blockIdx.x * blockDim.x + t) >> 6;
  int lane = t & 63;
  int wv = t >> 6;
  int c = lane & 31, half = lane >> 5;
  int beg = offs[wid], end = offs[wid + 1];
  float acc = 0.f;
  for (int p = beg + half; p < end; p += 2) {
    int src = srcs[p];
    acc += dinv[src] * hW[src * LATC + c];
  }
  acc += __shfl_xor(acc, 32);
  if (lane < 32) {
    float v = elu1(dinv[wid] * acc + b1[c]);
    h1[wid * LATC + c] = v;
    rowbuf[wv][c] = v;  // same-wave LDS: no barrier needed
  }
  int h = lane >> 3, k = lane & 7;
  float ps = 0.f, pd = 0.f;
#pragma unroll
  for (int j = 0; j < 4; ++j) {
    float x = rowbuf[wv][k * 4 + j];
    ps += x * va[h * 32 + k * 4 + j];
    pd += x * vb[h * 32 + k * 4 + j];
  }
  ps += __shfl_xor(ps, 1); pd += __shfl_xor(pd, 1);
  ps += __shfl_xor(ps, 2); pd += __shfl_xor(pd, 2);
  ps += __shfl_xor(ps, 4); pd += __shfl_xor(pd, 4);
  if (k == 0) {
    s[wid * HH + h] = ps;
    d[wid * HH + h] = pd;
  }
}

// ---- FUSED GAT1 aggregate + projection + bias + ELU --------------------
// 512 threads (8 waves) share ONE 32KB Ws copy -> 24 waves/CU (vs 16 at
// 256-thr blocks where 36.5KB LDS capped occupancy at 35%). Per-wave,
// barrier-free; aggs stride 33 keeps heads on distinct banks.
__launch_bounds__(512)
__global__ void gat1_aggproj_kernel(const float* __restrict__ h1,
                                    const float* __restrict__ s,
                                    const float* __restrict__ d,
                                    const int* offs, const int* srcs,
                                    const float* __restrict__ Wg1,
                                    const float* __restrict__ bg,
                                    float* __restrict__ h2) {
  __shared__ float Ws[32][HLC];   // 32 KB (shared by all 8 waves)
  __shared__ float aggs[8][264];  // 8.25 KB, stride-33 heads
  int t = threadIdx.x;
  {
    const float4* Wv = (const float4*)Wg1;
    float4* Bv = (float4*)Ws;
#pragma unroll
    for (int i = 0; i < 4; ++i) Bv[t + i * 512] = Wv[t + i * 512];
  }
  __syncthreads();
  int lane = t & 63;
  int wv = t >> 6;  // 0..7
  int g = lane >> 5, l5 = lane & 31;
  int h = l5 >> 2, c8 = (l5 & 3) * 8;
  int qb = lane * 4, hq = lane >> 3;
  float4 bb = *(const float4*)(bg + qb);
  for (int wid = blockIdx.x * 8 + wv; wid < NN; wid += AGP_BLOCKS * 8) {
    int beg = offs[wid], end = offs[wid + 1];
    float dn = d[wid * HH + h];
    float self = s[wid * HH + h] + dn;
    float m = self > 0.f ? self : 0.2f * self;  // self-loop always present
    float z = 0.f;
    float a[8] = {};
#pragma unroll 2
    for (int p = beg + g; p < end; p += 2) {
      int src = srcs[p];
      float sv = s[src * HH + h] + dn;
      float logit = sv > 0.f ? sv : 0.2f * sv;
      float e = __expf(logit - m);
      z += e;
      float4 v0 = *(const float4*)(h1 + (size_t)src * LATC + c8);
      float4 v1 = *(const float4*)(h1 + (size_t)src * LATC + c8 + 4);
      a[0] += e * v0.x; a[1] += e * v0.y; a[2] += e * v0.z; a[3] += e * v0.w;
      a[4] += e * v1.x; a[5] += e * v1.y; a[6] += e * v1.z; a[7] += e * v1.w;
    }
    z += __shfl_xor(z, 32);
#pragma unroll
    for (int j = 0; j < 8; ++j) a[j] += __shfl_xor(a[j], 32);
    float zinv = 1.f / (z + 1e-16f);
    if (g == 0) {
#pragma unroll
      for (int j = 0; j < 8; ++j)
        aggs[wv][h * 33 + c8 + j] = a[j] * zinv;  // same-wave LDS use
    }
    // projection: out[q] = sum_c agg[hq*33+c] * Wg1[c][q], q = qb..qb+3
    float o0 = bb.x, o1 = bb.y, o2 = bb.z, o3 = bb.w;
#pragma unroll 8
    for (int cc = 0; cc < 32; ++cc) {
      float av = aggs[wv][hq * 33 + cc];  // broadcast within head group
      float4 w4 = *(const float4*)(&Ws[cc][qb]);
      o0 += av * w4.x; o1 += av * w4.y; o2 += av * w4.z; o3 += av * w4.w;
    }
    *(float4*)(h2 + (size_t)wid * HLC + qb) =
        make_float4(elu1(o0), elu1(o1), elu1(o2), elu1(o3));
  }
}

// ---- GAT2 aggregate: bf16 hg gather, one wave per node -----------------
__global__ void gat_agg_kernel(const ushortT* __restrict__ hgb,
                               const float* __restrict__ s,
                               const float* __restrict__ dd, const int* offs,
                               const int* srcs, const float* bg, float* out) {
  int wid = (blockIdx.x * blockDim.x + threadIdx.x) >> 6;
  if (wid >= NN) return;
  int lane = threadIdx.x & 63;
  int hh = lane >> 3;
  int ch = lane << 2;
  int beg = offs[wid], end = offs[wid + 1];
  float dn = dd[wid * HH + hh];
  float self = s[wid * HH + hh] + dn;
  float m = self > 0.f ? self : 0.2f * self;
  float z = 0.f;
  float ax = 0.f, ay = 0.f, az = 0.f, aw = 0.f;
#pragma unroll 4
  for (int p = beg; p < end; ++p) {
    int src = srcs[p];
    float xv = s[src * HH + hh] + dn;
    float logit = xv > 0.f ? xv : 0.2f * xv;
    float e = __expf(logit - m);
    z += e;
    ushort4 v = *(const ushort4*)(hgb + (size_t)src * HLC + ch);
    ax += e * bf2f(v.x); ay += e * bf2f(v.y);
    az += e * bf2f(v.z); aw += e * bf2f(v.w);
  }
  float zinv = 1.f / (z + 1e-16f);
  float4 bb = *(const float4*)(bg + ch);
  float4 o;
  o.x = elu1(ax * zinv + bb.x); o.y = elu1(ay * zinv + bb.y);
  o.z = elu1(az * zinv + bb.z); o.w = elu1(aw * zinv + bb.w);
  *(float4*)(out + (size_t)wid * HLC + ch) = o;
}

// ---- readout head + fused loss (last-block ticket) ---------------------
__global__ void head_kernel(const float* __restrict__ h1,
                            const float* __restrict__ h2,
                            const float* __restrict__ h3, const int* batch,
                            const int* y, const float* __restrict__ Wl1,
                            const float* bl1, const float* __restrict__ Wl2,
                            const float* bl2, float* out, float* lterms,
                            int* done) {
  int g = blockIdx.x, tid = threadIdx.x;
  __shared__ float cat[544];
  __shared__ float hidden[HIDN];
  __shared__ float raw_s[2];
  __shared__ int idx_s;
  if (tid == 0) {
    int lo = 0, hi = NN;
    while (lo < hi) { int mid = (lo + hi) >> 1; if (batch[mid] < g) lo = mid + 1; else hi = mid; }
    idx_s = lo;
  }
  __syncthreads();
  int idx = idx_s;
  if (tid < 32) cat[tid] = h1[idx * LATC + tid];
  for (int i = tid; i < HLC; i += HIDN) {
    cat[32 + i] = h2[(size_t)idx * HLC + i];
    cat[288 + i] = h3[(size_t)idx * HLC + i];
  }
  __syncthreads();
  float f = bl1[tid];
  for (int k = 0; k < 544; ++k) f += cat[k] * Wl1[k * HIDN + tid];
  out[641 + g * HIDN + tid] = f;
  hidden[tid] = elu1(f);
  __syncthreads();
  if (tid < 2) {
    float r = bl2[tid];
    for (int j = 0; j < HIDN; ++j) r += hidden[j] * Wl2[j * 2 + tid];
    raw_s[tid] = r;
  }
  __syncthreads();
  if (tid == 0) {
    float r0 = raw_s[0], r1 = raw_s[1];
    float mx = fmaxf(r0, r1);
    float e0 = expf(r0 - mx), e1 = expf(r1 - mx);
    float zz = e0 + e1;
    float lse = mx + logf(zz);
    float lg0 = r0 - lse, lg1 = r1 - lse;
    out[g * 2 + 0] = lg0; out[g * 2 + 1] = lg1;
    out[385 + g * 2 + 0] = e0 / zz; out[385 + g * 2 + 1] = e1 / zz;
    out[257 + g] = (r1 > r0) ? 1.f : 0.f;
    lterms[g] = -((y[g] == 0) ? lg0 : lg1);
    __threadfence();
    int ticket = atomicAdd(done, 1);
    if (ticket == GG - 1) {  // last graph: deterministic fixed-order sum
      __threadfence();
      float sum = 0.f;
      for (int j = 0; j < GG; ++j) sum += lterms[j];
      out[256] = sum / (float)GG;
    }
  }
}

// ------------------------------------------------------------------------
extern "C" void kernel_launch(void* const* d_in, const int* in_sizes, int n_in,
                              void* d_out, int out_size, void* d_ws,
                              size_t ws_size, hipStream_t stream) {
  const float* x = (const float*)d_in[0];
  const int* ei = (const int*)d_in[1];
  const int* batch = (const int*)d_in[2];
  const int* y = (const int*)d_in[3];
  const float* W1 = (const float*)d_in[4];
  const float* b1 = (const float*)d_in[5];
  const float* Wg1 = (const float*)d_in[6];
  const float* asrc1 = (const float*)d_in[7];
  const float* adst1 = (const float*)d_in[8];
  const float* bg1 = (const float*)d_in[9];
  const float* Wg2 = (const float*)d_in[10];
  const float* asrc2 = (const float*)d_in[11];
  const float* adst2 = (const float*)d_in[12];
  const float* bg2 = (const float*)d_in[13];
  const float* Wl1 = (const float*)d_in[14];
  const float* bl1 = (const float*)d_in[15];
  const float* Wl2 = (const float*)d_in[16];
  const float* bl2 = (const float*)d_in[17];
  float* out = (float*)d_out;

  const int* erow = ei;
  const int* ecol = ei + EE;

  char* p = (char*)d_ws;
  auto alloc = [&](size_t bytes) {
    void* r = (void*)p;
    p += (bytes + 255) & ~(size_t)255;
    return r;
  };
  int* cntcur = (int*)alloc(((size_t)2 * NN + 64) * 4);  // cnt|cursor|done
  int* cnt = cntcur;
  int* cursor = cntcur + NN;
  int* done = cntcur + 2 * NN;
  int* offs = (int*)alloc((NN + 1) * 4);
  int* srcs = (int*)alloc((size_t)EP * 4);
  int* bsum = (int*)alloc(SCAN_G * 4);
  int* ebsum = (int*)alloc(SCAN_G * 4);
  float* dinv = (float*)alloc(NN * 4);
  float* hW = (float*)alloc((size_t)NN * LATC * 4);
  float* h1 = (float*)alloc((size_t)NN * LATC * 4);
  float* hg = (float*)alloc((size_t)NN * HLC * 4);  // hgb (bf16) backing
  float* h2 = (float*)alloc((size_t)NN * HLC * 4);
  float* h3 = (float*)alloc((size_t)NN * HLC * 4);
  float* sbuf = (float*)alloc((size_t)NN * HH * 4);
  float* dbuf = (float*)alloc((size_t)NN * HH * 4);
  float* va = (float*)alloc(HLC * 4);
  float* vb = (float*)alloc(HLC * 4);
  float* lterms = (float*)alloc(GG * 4);
  ushortT* whT = (ushortT*)alloc((size_t)HLC * HLC * 2);
  ushortT* wlT = (ushortT*)alloc((size_t)HLC * HLC * 2);
  ushortT* hgb = (ushortT*)hg;

  const int NBLK = (NN + 63) / 64;  // 782

  // CSR (reused by all three conv layers)
  hipMemsetAsync(cntcur, 0, ((size_t)2 * NN + 64) * 4, stream);
  count_kernel<<<(EE + 255) / 256, 256, 0, stream>>>(ecol, cnt);
  scan_part_kernel<<<SCAN_G, SCAN_B, 0, stream>>>(cnt, bsum);
  scan_top_kernel<<<1, 256, 0, stream>>>(bsum, ebsum, offs + NN);
  scan_final_kernel<<<SCAN_G, SCAN_B, 0, stream>>>(cnt, ebsum, offs, dinv);
  build_kernel<<<(EP + 255) / 256, 256, 0, stream>>>(erow, ecol, offs, cursor, srcs);
  finalize_kernel<<<(NN + 3) / 4, 256, 0, stream>>>(offs, srcs);

  // independent weight prep
  wsplit_kernel<<<(HLC * HLC + 255) / 256, 256, 0, stream>>>(Wg2, whT, wlT);
  prep_kernel<<<1, 256, 0, stream>>>(Wg1, asrc1, adst1, va, vb);

  // GCN (+ fused GAT1 s/d logits, va/vb from global)
  gemm_in_kernel<<<(NN + 255) / 256, 256, 0, stream>>>(x, W1, hW);
  gcn_agg_sd_kernel<<<(NN + 3) / 4, 256, 0, stream>>>(
      hW, offs, srcs, dinv, b1, va, vb, h1, sbuf, dbuf);

  // GAT 1 — fused gather + projection (8-wave blocks, shared Ws)
  gat1_aggproj_kernel<<<AGP_BLOCKS, 512, 0, stream>>>(h1, sbuf, dbuf, offs,
                                                      srcs, Wg1, bg1, h2);

  // GAT 2 — split-bf16 MFMA GEMM + exact s/d epilogue + bf16 hg
  gemm_gat2_mfma<<<NBLK, 256, 0, stream>>>(h2, whT, wlT, asrc2, adst2, hgb,
                                           sbuf, dbuf);
  gat_agg_kernel<<<(NN + 3) / 4, 256, 0, stream>>>(hgb, sbuf, dbuf, offs, srcs, bg2, h3);

  // head (+ fused loss)
  head_kernel<<<GG, HIDN, 0, stream>>>(h1, h2, h3, batch, y, Wl1, bl1, Wl2,
                                       bl2, out, lterms, done);
}

// Round 18
// 352.459 us; speedup vs baseline: 1.0601x; 1.0117x over previous
//
#include <hip/hip_runtime.h>
#include <math.h>

#define NN 50000
#define EE 640000
#define EP (EE + NN)
#define GG 128
#define IND 128
#define LATC 32
#define HH 8
#define HLC 256
#define HIDN 128
#define SCAN_B 256
#define SCAN_G ((NN + SCAN_B - 1) / SCAN_B)  // 196
#define AGP_BLOCKS 2048

typedef unsigned short ushortT;
typedef unsigned int uintT;
typedef short bf16x8 __attribute__((ext_vector_type(8)));
typedef float f32x4 __attribute__((ext_vector_type(4)));

__device__ __forceinline__ float elu1(float v) { return v > 0.f ? v : (__expf(v) - 1.f); }

__device__ __forceinline__ ushortT f2bf(float f) {  // round-to-nearest-even
  unsigned int u = __float_as_uint(f);
  return (ushortT)((u + 0x7fffu + ((u >> 16) & 1u)) >> 16);
}
__device__ __forceinline__ float bf2f(ushortT s) {
  return __uint_as_float(((unsigned int)s) << 16);
}

// ---- CSR build ----------------------------------------------------------
__global__ void count_kernel(const int* col, int* cnt) {
  int t = blockIdx.x * blockDim.x + threadIdx.x;
  if (t < EE) atomicAdd(&cnt[col[t]], 1);
}

// hierarchical exclusive scan over (cnt[i]+1): part -> top -> final
__global__ void scan_part_kernel(const int* __restrict__ cnt,
                                 int* __restrict__ bsum) {
  int t = threadIdx.x;
  int i = blockIdx.x * SCAN_B + t;
  int v = (i < NN) ? cnt[i] + 1 : 0;  // +1 = self-loop
#pragma unroll
  for (int d = 1; d < 64; d <<= 1) v += __shfl_xor(v, d);
  __shared__ int ws[4];
  if ((t & 63) == 0) ws[t >> 6] = v;
  __syncthreads();
  if (t == 0) bsum[blockIdx.x] = ws[0] + ws[1] + ws[2] + ws[3];
}

__global__ void scan_top_kernel(const int* __restrict__ bsum,
                                int* __restrict__ ebsum,
                                int* __restrict__ offs_last) {
  int t = threadIdx.x;  // 256 threads, SCAN_G=196 values
  int v = (t < SCAN_G) ? bsum[t] : 0;
  int orig = v;
  int lane = t & 63, w = t >> 6;
#pragma unroll
  for (int d = 1; d < 64; d <<= 1) {
    int o = __shfl_up(v, d);
    if (lane >= d) v += o;
  }
  __shared__ int ws[4];
  if (lane == 63) ws[w] = v;
  __syncthreads();
  int add = 0;
  for (int j = 0; j < w; ++j) add += ws[j];
  v += add;
  if (t < SCAN_G) ebsum[t] = v - orig;   // exclusive block prefix
  if (t == SCAN_G - 1) *offs_last = v;   // total = EP
}

__global__ void scan_final_kernel(const int* __restrict__ cnt,
                                  const int* __restrict__ ebsum,
                                  int* __restrict__ offs,
                                  float* __restrict__ dinv) {
  int t = threadIdx.x;
  int i = blockIdx.x * SCAN_B + t;
  int v = (i < NN) ? cnt[i] + 1 : 0;
  int orig = v;
  int lane = t & 63, w = t >> 6;
#pragma unroll
  for (int d = 1; d < 64; d <<= 1) {
    int o = __shfl_up(v, d);
    if (lane >= d) v += o;
  }
  __shared__ int ws[4];
  if (lane == 63) ws[w] = v;
  __syncthreads();
  int add = ebsum[blockIdx.x];
  for (int j = 0; j < w; ++j) add += ws[j];
  if (i < NN) {
    offs[i] = v - orig + add;            // exclusive scan
    dinv[i] = 1.f / sqrtf((float)orig);  // deg incl. self-loop
  }
}

__global__ void build_kernel(const int* row, const int* col, const int* offs,
                             int* cursor, int* srcs) {
  int t = blockIdx.x * blockDim.x + threadIdx.x;
  if (t >= EP) return;
  int r, c;
  if (t < EE) { r = row[t]; c = col[t]; } else { r = t - EE; c = r; }
  int pos = offs[c] + atomicAdd(&cursor[c], 1);
  srcs[pos] = r;
}

// one WAVE per node: 64-wide bitonic shuffle sort (canonical order ->
// deterministic FP sums); serial fallback for deg>64 (never hit here).
__global__ void finalize_kernel(const int* offs, int* srcs) {
  int gw = (blockIdx.x * blockDim.x + threadIdx.x) >> 6;
  if (gw >= NN) return;
  int lane = threadIdx.x & 63;
  int beg = offs[gw], end = offs[gw + 1];
  int deg = end - beg;
  if (deg <= 64) {
    int v = (lane < deg) ? srcs[beg + lane] : 0x7fffffff;
    for (int k = 2; k <= 64; k <<= 1)
      for (int j = k >> 1; j > 0; j >>= 1) {
        int o = __shfl_xor(v, j);
        bool keepmin = (((lane & k) == 0) == ((lane & j) == 0));
        v = keepmin ? (v < o ? v : o) : (v > o ? v : o);
      }
    if (lane < deg) srcs[beg + lane] = v;
  } else if (lane == 0) {
    for (int i = beg + 1; i < end; ++i) {
      int v = srcs[i]; int j = i - 1;
      while (j >= beg && srcs[j] > v) { srcs[j + 1] = srcs[j]; --j; }
      srcs[j + 1] = v;
    }
  }
}

// ---- GAT1 prep: va[h*32+c] = sum_j Wg1[c][h*32+j]*asrc[h*32+j] ---------
__global__ void prep_kernel(const float* __restrict__ Wg1,
                            const float* __restrict__ asrc,
                            const float* __restrict__ adst, float* va,
                            float* vb) {
  int t = threadIdx.x;  // 256 = 8 heads x 32 c
  int c = t & 31, h = t >> 5;
  float sa = 0.f, sb = 0.f;
  for (int j = 0; j < 32; ++j) {
    float w = Wg1[(size_t)c * HLC + h * 32 + j];
    sa += w * asrc[h * 32 + j];
    sb += w * adst[h * 32 + j];
  }
  va[t] = sa;  // t = h*32+c
  vb[t] = sb;
}

// ---- x@W1: [N,128] @ [128,32], 256 rows/block, 8x4 per thread ----------
__launch_bounds__(256)
__global__ void gemm_in_kernel(const float* __restrict__ A,
                               const float* __restrict__ W,
                               float* __restrict__ out) {
  __shared__ float As[32][264];
  __shared__ float Bs[32][32];
  int bm = blockIdx.x * 256;
  int tid = threadIdx.x;
  int tx = tid & 7, ty = tid >> 3;
  float acc[8][4] = {};
  for (int k0 = 0; k0 < IND; k0 += 32) {
    {
      int gm = bm + tid;
      bool ok = gm < NN;
#pragma unroll
      for (int j = 0; j < 8; ++j) {
        float4 v = ok ? *(const float4*)(A + (size_t)gm * IND + k0 + j * 4)
                      : make_float4(0.f, 0.f, 0.f, 0.f);
        As[j * 4 + 0][tid] = v.x; As[j * 4 + 1][tid] = v.y;
        As[j * 4 + 2][tid] = v.z; As[j * 4 + 3][tid] = v.w;
      }
    }
#pragma unroll
    for (int j = 0; j < 4; ++j) {
      int idx = tid + j * 256;
      int kk = idx >> 5, c = idx & 31;
      Bs[kk][c] = W[(size_t)(k0 + kk) * LATC + c];
    }
    __syncthreads();
#pragma unroll 4
    for (int kk = 0; kk < 32; ++kk) {
      float4 a0 = *(const float4*)(&As[kk][ty * 8]);
      float4 a1 = *(const float4*)(&As[kk][ty * 8 + 4]);
      float4 b = *(const float4*)(&Bs[kk][tx * 4]);
      float ar[8] = {a0.x, a0.y, a0.z, a0.w, a1.x, a1.y, a1.z, a1.w};
      float bc[4] = {b.x, b.y, b.z, b.w};
#pragma unroll
      for (int i = 0; i < 8; ++i)
#pragma unroll
        for (int j = 0; j < 4; ++j) acc[i][j] += ar[i] * bc[j];
    }
    __syncthreads();
  }
#pragma unroll
  for (int i = 0; i < 8; ++i) {
    int gm = bm + ty * 8 + i;
    if (gm < NN)
      *(float4*)(out + (size_t)gm * LATC + tx * 4) =
          make_float4(acc[i][0], acc[i][1], acc[i][2], acc[i][3]);
  }
}

// ---- Wg2 pre-split: WhT/WlT[n][k] bf16 hi/lo (transposed) --------------
__global__ void wsplit_kernel(const float* __restrict__ Wg2,
                              ushortT* __restrict__ WhT,
                              ushortT* __restrict__ WlT) {
  int idx = blockIdx.x * 256 + threadIdx.x;
  if (idx >= HLC * HLC) return;
  int k = idx >> 8, n = idx & 255;
  float f = Wg2[idx];
  ushortT hi = f2bf(f);
  WhT[n * HLC + k] = hi;
  WlT[n * HLC + k] = f2bf(f - bf2f(hi));
}

// ---- GAT2 GEMM via split-bf16 MFMA (3 mfma ~ fp32 accuracy) ------------
__launch_bounds__(256)
__global__ void gemm_gat2_mfma(const float* __restrict__ A,
                               const ushortT* __restrict__ WhT,
                               const ushortT* __restrict__ WlT,
                               const float* __restrict__ asrc,
                               const float* __restrict__ adst,
                               ushortT* __restrict__ hgb,
                               float* __restrict__ sbuf,
                               float* __restrict__ dbuf) {
  __shared__ __align__(16) char smem[51200];
  ushortT* Ah = (ushortT*)smem;             // [64][40]
  ushortT* Al = Ah + 64 * 40;               // [64][40]  (ends at 10240B)
  ushortT* Bh = (ushortT*)(smem + 10240);   // [256][40]
  ushortT* Bl = Bh + 256 * 40;              // [256][40] (ends at 51200B)
  float* LDSf = (float*)(smem + 10240);     // overlay: [32][260] f32 (33280B)

  int tid = threadIdx.x;
  int lane = tid & 63;
  int w = tid >> 6;          // wave 0..3 -> col quadrant
  int l15 = lane & 15, lg = lane >> 4;
  int bm = blockIdx.x * 64;

  f32x4 zero4 = {0.f, 0.f, 0.f, 0.f};
  f32x4 acc[4][4];
#pragma unroll
  for (int mi = 0; mi < 4; ++mi)
#pragma unroll
    for (int ni = 0; ni < 4; ++ni) acc[mi][ni] = zero4;

  for (int k0 = 0; k0 < HLC; k0 += 32) {
    // stage A rows (fp32 -> hi/lo bf16)
    {
      int row = tid >> 2, kb = (tid & 3) * 8;
      int gm = bm + row;
      float f[8];
      if (gm < NN) {
        float4 u0 = *(const float4*)(A + (size_t)gm * HLC + k0 + kb);
        float4 u1 = *(const float4*)(A + (size_t)gm * HLC + k0 + kb + 4);
        f[0] = u0.x; f[1] = u0.y; f[2] = u0.z; f[3] = u0.w;
        f[4] = u1.x; f[5] = u1.y; f[6] = u1.z; f[7] = u1.w;
      } else {
#pragma unroll
        for (int j = 0; j < 8; ++j) f[j] = 0.f;
      }
      bf16x8 vh, vl;
#pragma unroll
      for (int j = 0; j < 8; ++j) {
        ushortT hi = f2bf(f[j]);
        vh[j] = (short)hi;
        vl[j] = (short)f2bf(f[j] - bf2f(hi));
      }
      *(bf16x8*)(Ah + row * 40 + kb) = vh;
      *(bf16x8*)(Al + row * 40 + kb) = vl;
    }
    // stage B slice from pre-split WhT/WlT (n = tid, 32 consecutive k)
    {
      const bf16x8* ph = (const bf16x8*)(WhT + (size_t)tid * HLC + k0);
      const bf16x8* pl = (const bf16x8*)(WlT + (size_t)tid * HLC + k0);
#pragma unroll
      for (int i = 0; i < 4; ++i) {
        *(bf16x8*)(Bh + tid * 40 + i * 8) = ph[i];
        *(bf16x8*)(Bl + tid * 40 + i * 8) = pl[i];
      }
    }
    __syncthreads();
    bf16x8 ah[4], al[4], bh[4], bl[4];
#pragma unroll
    for (int mi = 0; mi < 4; ++mi) {
      int off = (mi * 16 + l15) * 40 + lg * 8;
      ah[mi] = *(const bf16x8*)(Ah + off);
      al[mi] = *(const bf16x8*)(Al + off);
    }
#pragma unroll
    for (int ni = 0; ni < 4; ++ni) {
      int off = (w * 64 + ni * 16 + l15) * 40 + lg * 8;
      bh[ni] = *(const bf16x8*)(Bh + off);
      bl[ni] = *(const bf16x8*)(Bl + off);
    }
#pragma unroll
    for (int mi = 0; mi < 4; ++mi)
#pragma unroll
      for (int ni = 0; ni < 4; ++ni) {
        acc[mi][ni] = __builtin_amdgcn_mfma_f32_16x16x32_bf16(
            al[mi], bh[ni], acc[mi][ni], 0, 0, 0);
        acc[mi][ni] = __builtin_amdgcn_mfma_f32_16x16x32_bf16(
            ah[mi], bl[ni], acc[mi][ni], 0, 0, 0);
        acc[mi][ni] = __builtin_amdgcn_mfma_f32_16x16x32_bf16(
            ah[mi], bh[ni], acc[mi][ni], 0, 0, 0);
      }
    __syncthreads();
  }

  // ---- s/d epilogue from fp32 acc (exact logits) ----
  float av[4], bv[4];
#pragma unroll
  for (int ni = 0; ni < 4; ++ni) {
    int c = w * 64 + ni * 16 + l15;
    av[ni] = asrc[c];
    bv[ni] = adst[c];
  }
#pragma unroll
  for (int mi = 0; mi < 4; ++mi)
#pragma unroll
    for (int r = 0; r < 4; ++r) {
      int gm = bm + mi * 16 + lg * 4 + r;
      float s0 = acc[mi][0][r] * av[0] + acc[mi][1][r] * av[1];
      float s1 = acc[mi][2][r] * av[2] + acc[mi][3][r] * av[3];
      float d0 = acc[mi][0][r] * bv[0] + acc[mi][1][r] * bv[1];
      float d1 = acc[mi][2][r] * bv[2] + acc[mi][3][r] * bv[3];
#pragma unroll
      for (int m = 1; m <= 8; m <<= 1) {
        s0 += __shfl_xor(s0, m);
        s1 += __shfl_xor(s1, m);
        d0 += __shfl_xor(d0, m);
        d1 += __shfl_xor(d1, m);
      }
      if (l15 == 0 && gm < NN) {
        sbuf[gm * HH + 2 * w] = s0;
        sbuf[gm * HH + 2 * w + 1] = s1;
        dbuf[gm * HH + 2 * w] = d0;
        dbuf[gm * HH + 2 * w + 1] = d1;
      }
    }

  // ---- hg bf16 store via LDS repack (two 32-row passes) ----
#pragma unroll
  for (int p = 0; p < 2; ++p) {
    __syncthreads();
#pragma unroll
    for (int q = 0; q < 2; ++q) {
      int mi = 2 * p + q;
#pragma unroll
      for (int ni = 0; ni < 4; ++ni)
#pragma unroll
        for (int r = 0; r < 4; ++r) {
          int lrow = q * 16 + lg * 4 + r;
          LDSf[lrow * 260 + w * 64 + ni * 16 + l15] = acc[mi][ni][r];
        }
    }
    __syncthreads();
    int row = tid >> 3, cb = (tid & 7) * 32;
    int gm = bm + p * 32 + row;
    if (gm < NN) {
      uintT u[16];
#pragma unroll
      for (int i = 0; i < 8; ++i) {
        float4 v = *(const float4*)(LDSf + row * 260 + cb + i * 4);
        u[2 * i] = (uintT)f2bf(v.x) | ((uintT)f2bf(v.y) << 16);
        u[2 * i + 1] = (uintT)f2bf(v.z) | ((uintT)f2bf(v.w) << 16);
      }
      uintT* dst = (uintT*)(hgb + (size_t)gm * HLC + cb);
#pragma unroll
      for (int i = 0; i < 4; ++i) {
        uint4 s;
        s.x = u[4 * i]; s.y = u[4 * i + 1];
        s.z = u[4 * i + 2]; s.w = u[4 * i + 3];
        *(uint4*)(dst + 4 * i) = s;
      }
    }
  }
}

// ---- FUSED GCN aggregate + GAT1 s/d logits (va/vb precomputed) ---------
// Also emits bf16 h1 copy (3.2 MB -> fits per-XCD L2) for the gat1 gather.
__global__ void gcn_agg_sd_kernel(const float* __restrict__ hW,
                                  const int* offs, const int* srcs,
                                  const float* dinv, const float* b1,
                                  const float* __restrict__ vag,
                                  const float* __restrict__ vbg,
                                  float* h1, ushortT* __restrict__ h1b,
                                  float* s, float* d) {
  __shared__ float va[HLC], vb[HLC];
  __shared__ float rowbuf[4][LATC];
  int t = threadIdx.x;
  va[t] = vag[t];  // coalesced 2KB stage
  vb[t] = vbg[t];
  __syncthreads();
  int wid = (blockIdx.x * blockDim.x + t) >> 6;
  int lane = t & 63;
  int wv = t >> 6;
  int c = lane & 31, half = lane >> 5;
  int beg = offs[wid], end = offs[wid + 1];
  float acc = 0.f;
  for (int p = beg + half; p < end; p += 2) {
    int src = srcs[p];
    acc += dinv[src] * hW[src * LATC + c];
  }
  acc += __shfl_xor(acc, 32);
  if (lane < 32) {
    float v = elu1(dinv[wid] * acc + b1[c]);
    h1[wid * LATC + c] = v;
    h1b[wid * LATC + c] = f2bf(v);
    rowbuf[wv][c] = v;  // same-wave LDS: no barrier needed
  }
  int h = lane >> 3, k = lane & 7;
  float ps = 0.f, pd = 0.f;
#pragma unroll
  for (int j = 0; j < 4; ++j) {
    float x = rowbuf[wv][k * 4 + j];
    ps += x * va[h * 32 + k * 4 + j];
    pd += x * vb[h * 32 + k * 4 + j];
  }
  ps += __shfl_xor(ps, 1); pd += __shfl_xor(pd, 1);
  ps += __shfl_xor(ps, 2); pd += __shfl_xor(pd, 2);
  ps += __shfl_xor(ps, 4); pd += __shfl_xor(pd, 4);
  if (k == 0) {
    s[wid * HH + h] = ps;
    d[wid * HH + h] = pd;
  }
}

// ---- FUSED GAT1 aggregate + projection + bias + ELU --------------------
// 8-wave blocks share one 32KB Ws copy. Gather: 4-way edge parity over
// bf16 h1 (L2-resident); 16 lanes/edge, lane = head*2 + half16, each lane
// owns 16 bf16 channels (2x b128). Cross-group reduce: xor16 + xor32.
__launch_bounds__(512)
__global__ void gat1_aggproj_kernel(const ushortT* __restrict__ h1b,
                                    const float* __restrict__ s,
                                    const float* __restrict__ d,
                                    const int* offs, const int* srcs,
                                    const float* __restrict__ Wg1,
                                    const float* __restrict__ bg,
                                    float* __restrict__ h2) {
  __shared__ float Ws[32][HLC];   // 32 KB (shared by all 8 waves)
  __shared__ float aggs[8][264];  // 8.25 KB, stride-33 heads
  int t = threadIdx.x;
  {
    const float4* Wv = (const float4*)Wg1;
    float4* Bv = (float4*)Ws;
#pragma unroll
    for (int i = 0; i < 4; ++i) Bv[t + i * 512] = Wv[t + i * 512];
  }
  __syncthreads();
  int lane = t & 63;
  int wv = t >> 6;  // 0..7
  int g = lane >> 4;           // parity group 0..3
  int l4 = lane & 15;
  int h = l4 >> 1;             // head 0..7
  int c16 = (l4 & 1) * 16;     // 16-channel half of the 32-dim row
  int qb = lane * 4, hq = lane >> 3;
  float4 bb = *(const float4*)(bg + qb);
  for (int wid = blockIdx.x * 8 + wv; wid < NN; wid += AGP_BLOCKS * 8) {
    int beg = offs[wid], end = offs[wid + 1];
    float dn = d[wid * HH + h];
    float self = s[wid * HH + h] + dn;
    float m = self > 0.f ? self : 0.2f * self;  // self-loop always present
    float z = 0.f;
    float a[16] = {};
#pragma unroll 2
    for (int p = beg + g; p < end; p += 4) {
      int src = srcs[p];
      float sv = s[src * HH + h] + dn;
      float logit = sv > 0.f ? sv : 0.2f * sv;
      float e = __expf(logit - m);
      z += e;
      bf16x8 v0 = *(const bf16x8*)(h1b + (size_t)src * LATC + c16);
      bf16x8 v1 = *(const bf16x8*)(h1b + (size_t)src * LATC + c16 + 8);
#pragma unroll
      for (int j = 0; j < 8; ++j) {
        a[j] += e * bf2f((ushortT)v0[j]);
        a[8 + j] += e * bf2f((ushortT)v1[j]);
      }
    }
    z += __shfl_xor(z, 16);
    z += __shfl_xor(z, 32);
#pragma unroll
    for (int j = 0; j < 16; ++j) {
      a[j] += __shfl_xor(a[j], 16);
      a[j] += __shfl_xor(a[j], 32);
    }
    float zinv = 1.f / (z + 1e-16f);
    if (g == 0) {
#pragma unroll
      for (int j = 0; j < 16; ++j)
        aggs[wv][h * 33 + c16 + j] = a[j] * zinv;  // same-wave LDS use
    }
    // projection: out[q] = sum_c agg[hq*33+c] * Wg1[c][q], q = qb..qb+3
    float o0 = bb.x, o1 = bb.y, o2 = bb.z, o3 = bb.w;
#pragma unroll 8
    for (int cc = 0; cc < 32; ++cc) {
      float av = aggs[wv][hq * 33 + cc];  // broadcast within head group
      float4 w4 = *(const float4*)(&Ws[cc][qb]);
      o0 += av * w4.x; o1 += av * w4.y; o2 += av * w4.z; o3 += av * w4.w;
    }
    *(float4*)(h2 + (size_t)wid * HLC + qb) =
        make_float4(elu1(o0), elu1(o1), elu1(o2), elu1(o3));
  }
}

// ---- GAT2 aggregate: bf16 hg gather, one wave per node -----------------
__global__ void gat_agg_kernel(const ushortT* __restrict__ hgb,
                               const float* __restrict__ s,
                               const float* __restrict__ dd, const int* offs,
                               const int* srcs, const float* bg, float* out) {
  int wid = (blockIdx.x * blockDim.x + threadIdx.x) >> 6;
  if (wid >= NN) return;
  int lane = threadIdx.x & 63;
  int hh = lane >> 3;
  int ch = lane << 2;
  int beg = offs[wid], end = offs[wid + 1];
  float dn = dd[wid * HH + hh];
  float self = s[wid * HH + hh] + dn;
  float m = self > 0.f ? self : 0.2f * self;
  float z = 0.f;
  float ax = 0.f, ay = 0.f, az = 0.f, aw = 0.f;
#pragma unroll 4
  for (int p = beg; p < end; ++p) {
    int src = srcs[p];
    float xv = s[src * HH + hh] + dn;
    float logit = xv > 0.f ? xv : 0.2f * xv;
    float e = __expf(logit - m);
    z += e;
    ushort4 v = *(const ushort4*)(hgb + (size_t)src * HLC + ch);
    ax += e * bf2f(v.x); ay += e * bf2f(v.y);
    az += e * bf2f(v.z); aw += e * bf2f(v.w);
  }
  float zinv = 1.f / (z + 1e-16f);
  float4 bb = *(const float4*)(bg + ch);
  float4 o;
  o.x = elu1(ax * zinv + bb.x); o.y = elu1(ay * zinv + bb.y);
  o.z = elu1(az * zinv + bb.z); o.w = elu1(aw * zinv + bb.w);
  *(float4*)(out + (size_t)wid * HLC + ch) = o;
}

// ---- readout head + fused loss (last-block ticket) ---------------------
__global__ void head_kernel(const float* __restrict__ h1,
                            const float* __restrict__ h2,
                            const float* __restrict__ h3, const int* batch,
                            const int* y, const float* __restrict__ Wl1,
                            const float* bl1, const float* __restrict__ Wl2,
                            const float* bl2, float* out, float* lterms,
                            int* done) {
  int g = blockIdx.x, tid = threadIdx.x;
  __shared__ float cat[544];
  __shared__ float hidden[HIDN];
  __shared__ float raw_s[2];
  __shared__ int idx_s;
  if (tid == 0) {
    int lo = 0, hi = NN;
    while (lo < hi) { int mid = (lo + hi) >> 1; if (batch[mid] < g) lo = mid + 1; else hi = mid; }
    idx_s = lo;
  }
  __syncthreads();
  int idx = idx_s;
  if (tid < 32) cat[tid] = h1[idx * LATC + tid];
  for (int i = tid; i < HLC; i += HIDN) {
    cat[32 + i] = h2[(size_t)idx * HLC + i];
    cat[288 + i] = h3[(size_t)idx * HLC + i];
  }
  __syncthreads();
  float f = bl1[tid];
  for (int k = 0; k < 544; ++k) f += cat[k] * Wl1[k * HIDN + tid];
  out[641 + g * HIDN + tid] = f;
  hidden[tid] = elu1(f);
  __syncthreads();
  if (tid < 2) {
    float r = bl2[tid];
    for (int j = 0; j < HIDN; ++j) r += hidden[j] * Wl2[j * 2 + tid];
    raw_s[tid] = r;
  }
  __syncthreads();
  if (tid == 0) {
    float r0 = raw_s[0], r1 = raw_s[1];
    float mx = fmaxf(r0, r1);
    float e0 = expf(r0 - mx), e1 = expf(r1 - mx);
    float zz = e0 + e1;
    float lse = mx + logf(zz);
    float lg0 = r0 - lse, lg1 = r1 - lse;
    out[g * 2 + 0] = lg0; out[g * 2 + 1] = lg1;
    out[385 + g * 2 + 0] = e0 / zz; out[385 + g * 2 + 1] = e1 / zz;
    out[257 + g] = (r1 > r0) ? 1.f : 0.f;
    lterms[g] = -((y[g] == 0) ? lg0 : lg1);
    __threadfence();
    int ticket = atomicAdd(done, 1);
    if (ticket == GG - 1) {  // last graph: deterministic fixed-order sum
      __threadfence();
      float sum = 0.f;
      for (int j = 0; j < GG; ++j) sum += lterms[j];
      out[256] = sum / (float)GG;
    }
  }
}

// ------------------------------------------------------------------------
extern "C" void kernel_launch(void* const* d_in, const int* in_sizes, int n_in,
                              void* d_out, int out_size, void* d_ws,
                              size_t ws_size, hipStream_t stream) {
  const float* x = (const float*)d_in[0];
  const int* ei = (const int*)d_in[1];
  const int* batch = (const int*)d_in[2];
  const int* y = (const int*)d_in[3];
  const float* W1 = (const float*)d_in[4];
  const float* b1 = (const float*)d_in[5];
  const float* Wg1 = (const float*)d_in[6];
  const float* asrc1 = (const float*)d_in[7];
  const float* adst1 = (const float*)d_in[8];
  const float* bg1 = (const float*)d_in[9];
  const float* Wg2 = (const float*)d_in[10];
  const float* asrc2 = (const float*)d_in[11];
  const float* adst2 = (const float*)d_in[12];
  const float* bg2 = (const float*)d_in[13];
  const float* Wl1 = (const float*)d_in[14];
  const float* bl1 = (const float*)d_in[15];
  const float* Wl2 = (const float*)d_in[16];
  const float* bl2 = (const float*)d_in[17];
  float* out = (float*)d_out;

  const int* erow = ei;
  const int* ecol = ei + EE;

  char* p = (char*)d_ws;
  auto alloc = [&](size_t bytes) {
    void* r = (void*)p;
    p += (bytes + 255) & ~(size_t)255;
    return r;
  };
  int* cntcur = (int*)alloc(((size_t)2 * NN + 64) * 4);  // cnt|cursor|done
  int* cnt = cntcur;
  int* cursor = cntcur + NN;
  int* done = cntcur + 2 * NN;
  int* offs = (int*)alloc((NN + 1) * 4);
  int* srcs = (int*)alloc((size_t)EP * 4);
  int* bsum = (int*)alloc(SCAN_G * 4);
  int* ebsum = (int*)alloc(SCAN_G * 4);
  float* dinv = (float*)alloc(NN * 4);
  float* hW = (float*)alloc((size_t)NN * LATC * 4);
  float* h1 = (float*)alloc((size_t)NN * LATC * 4);
  ushortT* h1b = (ushortT*)alloc((size_t)NN * LATC * 2);
  float* hg = (float*)alloc((size_t)NN * HLC * 4);  // hgb (bf16) backing
  float* h2 = (float*)alloc((size_t)NN * HLC * 4);
  float* h3 = (float*)alloc((size_t)NN * HLC * 4);
  float* sbuf = (float*)alloc((size_t)NN * HH * 4);
  float* dbuf = (float*)alloc((size_t)NN * HH * 4);
  float* va = (float*)alloc(HLC * 4);
  float* vb = (float*)alloc(HLC * 4);
  float* lterms = (float*)alloc(GG * 4);
  ushortT* whT = (ushortT*)alloc((size_t)HLC * HLC * 2);
  ushortT* wlT = (ushortT*)alloc((size_t)HLC * HLC * 2);
  ushortT* hgb = (ushortT*)hg;

  const int NBLK = (NN + 63) / 64;  // 782

  // CSR (reused by all three conv layers)
  hipMemsetAsync(cntcur, 0, ((size_t)2 * NN + 64) * 4, stream);
  count_kernel<<<(EE + 255) / 256, 256, 0, stream>>>(ecol, cnt);
  scan_part_kernel<<<SCAN_G, SCAN_B, 0, stream>>>(cnt, bsum);
  scan_top_kernel<<<1, 256, 0, stream>>>(bsum, ebsum, offs + NN);
  scan_final_kernel<<<SCAN_G, SCAN_B, 0, stream>>>(cnt, ebsum, offs, dinv);
  build_kernel<<<(EP + 255) / 256, 256, 0, stream>>>(erow, ecol, offs, cursor, srcs);
  finalize_kernel<<<(NN + 3) / 4, 256, 0, stream>>>(offs, srcs);

  // independent weight prep
  wsplit_kernel<<<(HLC * HLC + 255) / 256, 256, 0, stream>>>(Wg2, whT, wlT);
  prep_kernel<<<1, 256, 0, stream>>>(Wg1, asrc1, adst1, va, vb);

  // GCN (+ fused GAT1 s/d logits + bf16 h1 copy)
  gemm_in_kernel<<<(NN + 255) / 256, 256, 0, stream>>>(x, W1, hW);
  gcn_agg_sd_kernel<<<(NN + 3) / 4, 256, 0, stream>>>(
      hW, offs, srcs, dinv, b1, va, vb, h1, h1b, sbuf, dbuf);

  // GAT 1 — fused gather (4-way parity, bf16 L2-resident) + projection
  gat1_aggproj_kernel<<<AGP_BLOCKS, 512, 0, stream>>>(h1b, sbuf, dbuf, offs,
                                                      srcs, Wg1, bg1, h2);

  // GAT 2 — split-bf16 MFMA GEMM + exact s/d epilogue + bf16 hg
  gemm_gat2_mfma<<<NBLK, 256, 0, stream>>>(h2, whT, wlT, asrc2, adst2, hgb,
                                           sbuf, dbuf);
  gat_agg_kernel<<<(NN + 3) / 4, 256, 0, stream>>>(hgb, sbuf, dbuf, offs, srcs, bg2, h3);

  // head (+ fused loss)
  head_kernel<<<GG, HIDN, 0, stream>>>(h1, h2, h3, batch, y, Wl1, bl1, Wl2,
                                       bl2, out, lterms, done);
}